// Round 1
// baseline (582.767 us; speedup 1.0000x reference)
//
#include <hip/hip_runtime.h>
#include <hip/hip_cooperative_groups.h>
#include <math.h>

namespace cg = cooperative_groups;

#define Bn 8
#define Nn 4096
#define Dn 512
#define Ln 64

// ---------------------------------------------------------------------------
// Shared-memory-tiled fp32 GEMM building block (unchanged from 5-kernel ver).
//   C_tile(64 x TN) += A[m0.., kbase..kbase+16*ksteps) @ Beff
//   BT=false: Beff[k][n] = B[k*512 + n];  BT=true: Beff[k][n] = B[n*512 + k]
//   NPART>1: A is NPART partials (stride apstride) summed during staging.
//   SCALE: multiply A row r by sv[r] during staging.
// 256 threads, micro-tile 4 x (TN/16).
// ---------------------------------------------------------------------------
template<int TN, bool BT, int NPART, bool SCALE>
__device__ __forceinline__ void gemm_tile(
    const float* A, size_t apstride, int m0,
    const float* B, int n0, int kbase, int ksteps,
    const float* sv,
    float* dst,
    float (*As)[68], float (*Bs)[132], int tid)
{
    const int ty = tid >> 4;
    const int tx = tid & 15;
    float acc[4][TN / 16];
    #pragma unroll
    for (int m = 0; m < 4; m++)
        #pragma unroll
        for (int n = 0; n < TN / 16; n++) acc[m][n] = 0.f;

    for (int s = 0; s < ksteps; s++) {
        const int k0 = kbase + s * 16;
        {
            int r = tid >> 2, kq = tid & 3;
            float4 v = *(const float4*)&A[(size_t)(m0 + r) * Dn + k0 + kq * 4];
            #pragma unroll
            for (int p = 1; p < NPART; p++) {
                float4 w = *(const float4*)&A[(size_t)p * apstride +
                                              (size_t)(m0 + r) * Dn + k0 + kq * 4];
                v.x += w.x; v.y += w.y; v.z += w.z; v.w += w.w;
            }
            if (SCALE) { float sc = sv[r]; v.x *= sc; v.y *= sc; v.z *= sc; v.w *= sc; }
            As[kq * 4 + 0][r] = v.x;
            As[kq * 4 + 1][r] = v.y;
            As[kq * 4 + 2][r] = v.z;
            As[kq * 4 + 3][r] = v.w;
        }
        #pragma unroll
        for (int rep = 0; rep < TN / 64; rep++) {
            int lin = tid + rep * 256;
            if (!BT) {
                int kk = lin / (TN / 4), jq = lin % (TN / 4);
                *(float4*)&Bs[kk][jq * 4] =
                    *(const float4*)&B[(size_t)(k0 + kk) * Dn + n0 + jq * 4];
            } else {
                int j = lin >> 2, kq = lin & 3;
                float4 v = *(const float4*)&B[(size_t)(n0 + j) * Dn + k0 + kq * 4];
                Bs[kq * 4 + 0][j] = v.x;
                Bs[kq * 4 + 1][j] = v.y;
                Bs[kq * 4 + 2][j] = v.z;
                Bs[kq * 4 + 3][j] = v.w;
            }
        }
        __syncthreads();
        #pragma unroll
        for (int kk = 0; kk < 16; kk++) {
            float4 a = *(const float4*)&As[kk][ty * 4];
            float av[4] = {a.x, a.y, a.z, a.w};
            if (TN == 64) {
                float4 b = *(const float4*)&Bs[kk][tx * 4];
                float bv[4] = {b.x, b.y, b.z, b.w};
                #pragma unroll
                for (int m = 0; m < 4; m++)
                    #pragma unroll
                    for (int n = 0; n < 4; n++) acc[m][n] += av[m] * bv[n];
            } else {
                float4 b0 = *(const float4*)&Bs[kk][tx * 8];
                float4 b1 = *(const float4*)&Bs[kk][tx * 8 + 4];
                float bv[8] = {b0.x, b0.y, b0.z, b0.w, b1.x, b1.y, b1.z, b1.w};
                #pragma unroll
                for (int m = 0; m < 4; m++)
                    #pragma unroll
                    for (int n = 0; n < 8; n++) acc[m][n % (TN/16)] += av[m] * bv[n];
            }
        }
        __syncthreads();
    }
    #pragma unroll
    for (int m = 0; m < 4; m++) {
        size_t base = (size_t)(m0 + ty * 4 + m) * Dn + n0;
        if (TN == 64) {
            float4 o = {acc[m][0], acc[m][1], acc[m][2], acc[m][3]};
            *(float4*)&dst[base + tx * 4] = o;
        } else {
            float4 o0 = {acc[m][0], acc[m][1], acc[m][2], acc[m][3]};
            float4 o1 = {acc[m][4], acc[m][5], acc[m][6], acc[m][7]};
            *(float4*)&dst[base + tx * 8] = o0;
            *(float4*)&dst[base + tx * 8 + 4] = o1;
        }
    }
}

// ============================================================================
// Single cooperative kernel: 512 blocks x 256 threads, 4 grid syncs.
//   P1: Wov partials (0..255), q partials (256..287), woz partials (288..319),
//       mask compaction (320..327)
//   P2: qk partials (0..63), wov = sum wp (64..319)
//   P3: token pass, one block per (sample, segment)  [all 512]
//   P4: op partials = (s/den) @ wov^T  (0..255)      [op aliases wp]
//   P5: epilogue select/sum                          (0..255)
// LDS ~22 KB/block -> 2 blocks/CU co-resident; VGPR well under the 8-wave cap.
// ============================================================================
__global__ void __launch_bounds__(256) k_fused(
    const float* __restrict__ feats, const unsigned char* __restrict__ maskbytes,
    const float* __restrict__ z, const float* __restrict__ Wq,
    const float* __restrict__ Wk, const float* __restrict__ Wv,
    const float* __restrict__ Wo, const float* __restrict__ bo,
    float* __restrict__ out,
    int* nvalid, int* idx, float* qp, float* wozp, float* qkp,
    float* wov, float* sbuf, float* den, float* wp)
{
    cg::grid_group grid = cg::this_grid();

    __shared__ float As[16][68];
    __shared__ float Bs[16][132];
    __shared__ int scanbuf[256];
    __shared__ int cflags[4];
    __shared__ float sred[4 * Dn];
    __shared__ float dred[4];
    __shared__ float ssv[64];

    int tid = threadIdx.x;
    int gb = blockIdx.x;

    // --------------------------- Phase 1 ---------------------------
    if (gb < 256) {               // Wov = Wo @ Wv, Ksplit8 (K-slice 64)
        int ks = gb & 7;  int t = gb >> 3;
        int rt = t >> 2, ct = t & 3;
        gemm_tile<128, false, 1, false>(Wo, 0, rt * 64, Wv, ct * 128,
                                        ks * 64, 4, nullptr,
                                        wp + (size_t)ks * 262144, As, Bs, tid);
    } else if (gb < 288) {        // q = z @ Wq^T, Ksplit4
        int t = gb - 256; int ks = t & 3; int nt = t >> 2;
        gemm_tile<64, true, 1, false>(z, 0, 0, Wq, nt * 64,
                                      ks * 128, 8, nullptr,
                                      qp + (size_t)ks * 32768, As, Bs, tid);
    } else if (gb < 320) {        // woz = z @ Wo^T, Ksplit4
        int t = gb - 288; int ks = t & 3; int nt = t >> 2;
        gemm_tile<64, true, 1, false>(z, 0, 0, Wo, nt * 64,
                                      ks * 128, 8, nullptr,
                                      wozp + (size_t)ks * 32768, As, Bs, tid);
    } else if (gb < 328) {        // mask compaction, one block per sample
        int b = gb - 320;
        if (tid == 0) { cflags[0] = 0; cflags[1] = 0; cflags[2] = 0; }
        __syncthreads();
        int lge2 = 0, lb1 = 0, lm = 0;
        for (int p = tid; p < 4096; p += 256) {
            unsigned int v = maskbytes[p];
            if (v > 1u) lge2 = 1;
            if (v != 0u) {
                if ((p & 3) == 1) lb1 = 1;
                if ((p & 3) != 0) lm = 1;
            }
        }
        if (lge2) atomicOr(&cflags[0], 1);
        if (lb1)  atomicOr(&cflags[1], 1);
        if (lm)   atomicOr(&cflags[2], 1);
        __syncthreads();
        if (tid == 0) cflags[3] = cflags[0] ? (cflags[1] ? 2 : 4) : (cflags[2] ? 1 : 4);
        __syncthreads();
        int w = cflags[3];

        int base = tid * 16;
        int cnt = 0;
        int validbits[16];
        for (int e = 0; e < 16; e++) {
            int i = base + e;
            size_t byteoff = ((size_t)b * Nn + i) * (size_t)w;
            unsigned int nz = 0;
            for (int q = 0; q < w; q++) nz |= maskbytes[byteoff + q];
            int valid = (nz == 0) ? 1 : 0;
            validbits[e] = valid;
            cnt += valid;
        }
        scanbuf[tid] = cnt;
        __syncthreads();
        for (int off = 1; off < 256; off <<= 1) {
            int v = (tid >= off) ? scanbuf[tid - off] : 0;
            __syncthreads();
            scanbuf[tid] += v;
            __syncthreads();
        }
        int pos = scanbuf[tid] - cnt;
        for (int e = 0; e < 16; e++) {
            if (validbits[e]) { idx[b * Nn + pos] = base + e; pos++; }
        }
        if (tid == 255) nvalid[b] = scanbuf[255];
    }
    __threadfence();
    grid.sync();

    // --------------------------- Phase 2 ---------------------------
    if (gb < 64) {                // qk partials = (sum qp) @ Wk, Ksplit8
        int ks = gb & 7; int nt = gb >> 3;
        gemm_tile<64, false, 4, false>(qp, 32768, 0, Wk, nt * 64,
                                       ks * 64, 4, nullptr,
                                       qkp + (size_t)ks * 32768, As, Bs, tid);
    } else if (gb < 320) {        // wov = sum of 8 wp partials
        int lin = (gb - 64) * 256 + tid;
        float4 v = {0.f, 0.f, 0.f, 0.f};
        #pragma unroll
        for (int p = 0; p < 8; p++) {
            float4 w = *(const float4*)&wp[(size_t)p * 262144 + (size_t)lin * 4];
            v.x += w.x; v.y += w.y; v.z += w.z; v.w += w.w;
        }
        *(float4*)&wov[(size_t)lin * 4] = v;
    }
    __threadfence();
    grid.sync();

    // --------------------------- Phase 3: token pass ---------------------------
    {
        int wv = tid >> 6;
        int lane = tid & 63;
        int b = gb / Ln;
        int l = gb % Ln;
        int nv = nvalid[b];
        int seg_size = nv / Ln; if (seg_size < 1) seg_size = 1;
        int used = Ln * seg_size; if (used > nv) used = nv;
        int r0 = l * seg_size;
        int r1 = r0 + seg_size; if (r1 > used) r1 = used;

        float4 qa = {0.f,0.f,0.f,0.f}, qb = {0.f,0.f,0.f,0.f};
        #pragma unroll
        for (int p = 0; p < 8; p++) {
            const float4* q4 = (const float4*)(qkp + (size_t)p * 32768 +
                                               (size_t)l * Dn + lane * 8);
            float4 a = q4[0], c = q4[1];
            qa.x += a.x; qa.y += a.y; qa.z += a.z; qa.w += a.w;
            qb.x += c.x; qb.y += c.y; qb.z += c.z; qb.w += c.w;
        }
        float qf[8] = {qa.x, qa.y, qa.z, qa.w, qb.x, qb.y, qb.z, qb.w};

        float sacc[8] = {0,0,0,0,0,0,0,0};
        float dacc = 0.f;
        const float inv_d = 1.0f / (float)Dn;
        const float inv_temp = 1.0f / 22.62741699796952f;  // 1/sqrt(512)

        for (int r = r0 + wv * 2; r < r1; r += 8) {
            int has2 = (r + 1 < r1);
            int t0 = idx[b * Nn + r];
            int t1 = has2 ? idx[b * Nn + r + 1] : t0;
            const float4* p0 = (const float4*)(feats + ((size_t)b * Nn + t0) * Dn + lane * 8);
            const float4* p1 = (const float4*)(feats + ((size_t)b * Nn + t1) * Dn + lane * 8);
            float4 xa0 = p0[0], xb0 = p0[1];
            float4 xa1 = p1[0], xb1 = p1[1];
            float x0[8] = {xa0.x, xa0.y, xa0.z, xa0.w, xb0.x, xb0.y, xb0.z, xb0.w};
            float x1[8] = {xa1.x, xa1.y, xa1.z, xa1.w, xb1.x, xb1.y, xb1.z, xb1.w};
            float sum0 = 0.f, ssq0 = 0.f, sum1 = 0.f, ssq1 = 0.f;
            #pragma unroll
            for (int j = 0; j < 8; j++) {
                sum0 += x0[j]; ssq0 += x0[j] * x0[j];
                sum1 += x1[j]; ssq1 += x1[j] * x1[j];
            }
            #pragma unroll
            for (int off = 32; off > 0; off >>= 1) {
                sum0 += __shfl_xor(sum0, off);
                ssq0 += __shfl_xor(ssq0, off);
                sum1 += __shfl_xor(sum1, off);
                ssq1 += __shfl_xor(ssq1, off);
            }
            float mu0 = sum0 * inv_d, mu1 = sum1 * inv_d;
            float rstd0 = rsqrtf(ssq0 * inv_d - mu0 * mu0 + 1e-5f);
            float rstd1 = rsqrtf(ssq1 * inv_d - mu1 * mu1 + 1e-5f);
            float ln0[8], ln1[8];
            float dot0 = 0.f, dot1 = 0.f;
            #pragma unroll
            for (int j = 0; j < 8; j++) {
                ln0[j] = (x0[j] - mu0) * rstd0; dot0 += ln0[j] * qf[j];
                ln1[j] = (x1[j] - mu1) * rstd1; dot1 += ln1[j] * qf[j];
            }
            #pragma unroll
            for (int off = 32; off > 0; off >>= 1) {
                dot0 += __shfl_xor(dot0, off);
                dot1 += __shfl_xor(dot1, off);
            }
            float lg0 = fminf(5.0f, fmaxf(-5.0f, dot0 * inv_temp));
            float lg1 = fminf(5.0f, fmaxf(-5.0f, dot1 * inv_temp));
            float e0 = expf(lg0);
            float e1 = has2 ? expf(lg1) : 0.f;
            #pragma unroll
            for (int j = 0; j < 8; j++) sacc[j] += e0 * ln0[j] + e1 * ln1[j];
            dacc += e0 + e1;
        }

        #pragma unroll
        for (int j = 0; j < 8; j++) sred[wv * Dn + lane * 8 + j] = sacc[j];
        if (lane == 0) dred[wv] = dacc;
        __syncthreads();
        for (int e = tid; e < Dn; e += 256) {
            float v = sred[e] + sred[Dn + e] + sred[2 * Dn + e] + sred[3 * Dn + e];
            sbuf[(size_t)gb * Dn + e] = v;
        }
        if (tid == 0) den[gb] = dred[0] + dred[1] + dred[2] + dred[3];
    }
    __threadfence();
    grid.sync();

    // --------------------------- Phase 4: op = (s/den) @ wov^T ---------------------------
    if (gb < 256) {
        int ks = gb & 7; int t = gb >> 3;
        int rt = t >> 2, ct = t & 3;
        int m0 = rt * 64;
        if (tid < 64) {
            float dv = den[m0 + tid];
            ssv[tid] = (dv > 0.f) ? 1.f / dv : 0.f;
        }
        __syncthreads();
        gemm_tile<128, true, 1, true>(sbuf, 0, m0, wov, ct * 128,
                                      ks * 64, 4, ssv,
                                      wp + (size_t)ks * 262144, As, Bs, tid);  // op aliases wp
    }
    __threadfence();
    grid.sync();

    // --------------------------- Phase 5: epilogue ---------------------------
    if (gb < 256) {
        const float* op = wp;   // alias
        int lin = gb * 256 + tid;   // 65536 float4s
        int row = lin >> 7;
        int col = (lin & 127) * 4;
        int b = row >> 6, l = row & 63;
        float4 v;
        if (nvalid[b] == 0) {
            v = *(const float4*)&z[(size_t)l * Dn + col];
        } else {
            float4 bv = *(const float4*)&bo[col];
            float dv = den[row];
            if (dv > 0.f) {
                float4 a = {0.f, 0.f, 0.f, 0.f};
                #pragma unroll
                for (int p = 0; p < 8; p++) {
                    float4 w = *(const float4*)&op[(size_t)p * 262144 + (size_t)row * Dn + col];
                    a.x += w.x; a.y += w.y; a.z += w.z; a.w += w.w;
                }
                v.x = a.x + bv.x; v.y = a.y + bv.y; v.z = a.z + bv.z; v.w = a.w + bv.w;
            } else {
                float4 a = {0.f, 0.f, 0.f, 0.f};
                #pragma unroll
                for (int p = 0; p < 4; p++) {
                    float4 w = *(const float4*)&wozp[(size_t)p * 32768 + (size_t)l * Dn + col];
                    a.x += w.x; a.y += w.y; a.z += w.z; a.w += w.w;
                }
                v.x = a.x + bv.x; v.y = a.y + bv.y; v.z = a.z + bv.z; v.w = a.w + bv.w;
            }
        }
        *(float4*)&out[(size_t)row * Dn + col] = v;
    }
}

extern "C" void kernel_launch(void* const* d_in, const int* in_sizes, int n_in,
                              void* d_out, int out_size, void* d_ws, size_t ws_size,
                              hipStream_t stream) {
    const float* feats = (const float*)d_in[0];
    // d_in[1] = coords: unused by the reference
    const unsigned char* maskb = (const unsigned char*)d_in[2];
    const float* z  = (const float*)d_in[3];
    const float* Wq = (const float*)d_in[4];
    const float* Wk = (const float*)d_in[5];
    const float* Wv = (const float*)d_in[6];
    const float* Wo = (const float*)d_in[7];
    const float* bo = (const float*)d_in[8];
    float* out = (float*)d_out;

    int*   nvalid = (int*)d_ws;
    int*   idx    = nvalid + 64;
    float* fbase  = (float*)(idx + Bn * Nn);
    float* qp     = fbase;                 // 4 x 32768
    float* wozp   = qp   + 4 * 32768;      // 4 x 32768
    float* qkp    = wozp + 4 * 32768;      // 8 x 32768
    float* wov    = qkp  + 8 * 32768;      // 262144
    float* sbuf   = wov  + 262144;         // 262144
    float* den    = sbuf + 262144;         // 1024 (padded)
    float* wp     = den  + 1024;           // 8 x 262144 (also op)

    void* kargs[] = {
        (void*)&feats, (void*)&maskb, (void*)&z, (void*)&Wq, (void*)&Wk,
        (void*)&Wv, (void*)&Wo, (void*)&bo, (void*)&out,
        (void*)&nvalid, (void*)&idx, (void*)&qp, (void*)&wozp, (void*)&qkp,
        (void*)&wov, (void*)&sbuf, (void*)&den, (void*)&wp
    };
    hipLaunchCooperativeKernel((const void*)k_fused, dim3(512), dim3(256),
                               kargs, 0, stream);
}

// Round 2
// 490.728 us; speedup vs baseline: 1.1876x; 1.1876x over previous
//
#include <hip/hip_runtime.h>
#include <math.h>

#define Bn 8
#define Nn 4096
#define Dn 512
#define Ln 64
#define NBLK 512

// ---------------------------------------------------------------------------
// Shared-memory-tiled fp32 GEMM building block (unchanged, verified).
//   C_tile(64 x TN) += A[m0.., kbase..kbase+16*ksteps) @ Beff
//   BT=false: Beff[k][n] = B[k*512 + n];  BT=true: Beff[k][n] = B[n*512 + k]
//   NPART>1: A is NPART partials (stride apstride) summed during staging.
//   SCALE: multiply A row r by sv[r] during staging.
// 256 threads, micro-tile 4 x (TN/16).
// ---------------------------------------------------------------------------
template<int TN, bool BT, int NPART, bool SCALE>
__device__ __forceinline__ void gemm_tile(
    const float* A, size_t apstride, int m0,
    const float* B, int n0, int kbase, int ksteps,
    const float* sv,
    float* dst,
    float (*As)[68], float (*Bs)[132], int tid)
{
    const int ty = tid >> 4;
    const int tx = tid & 15;
    float acc[4][TN / 16];
    #pragma unroll
    for (int m = 0; m < 4; m++)
        #pragma unroll
        for (int n = 0; n < TN / 16; n++) acc[m][n] = 0.f;

    for (int s = 0; s < ksteps; s++) {
        const int k0 = kbase + s * 16;
        {
            int r = tid >> 2, kq = tid & 3;
            float4 v = *(const float4*)&A[(size_t)(m0 + r) * Dn + k0 + kq * 4];
            #pragma unroll
            for (int p = 1; p < NPART; p++) {
                float4 w = *(const float4*)&A[(size_t)p * apstride +
                                              (size_t)(m0 + r) * Dn + k0 + kq * 4];
                v.x += w.x; v.y += w.y; v.z += w.z; v.w += w.w;
            }
            if (SCALE) { float sc = sv[r]; v.x *= sc; v.y *= sc; v.z *= sc; v.w *= sc; }
            As[kq * 4 + 0][r] = v.x;
            As[kq * 4 + 1][r] = v.y;
            As[kq * 4 + 2][r] = v.z;
            As[kq * 4 + 3][r] = v.w;
        }
        #pragma unroll
        for (int rep = 0; rep < TN / 64; rep++) {
            int lin = tid + rep * 256;
            if (!BT) {
                int kk = lin / (TN / 4), jq = lin % (TN / 4);
                *(float4*)&Bs[kk][jq * 4] =
                    *(const float4*)&B[(size_t)(k0 + kk) * Dn + n0 + jq * 4];
            } else {
                int j = lin >> 2, kq = lin & 3;
                float4 v = *(const float4*)&B[(size_t)(n0 + j) * Dn + k0 + kq * 4];
                Bs[kq * 4 + 0][j] = v.x;
                Bs[kq * 4 + 1][j] = v.y;
                Bs[kq * 4 + 2][j] = v.z;
                Bs[kq * 4 + 3][j] = v.w;
            }
        }
        __syncthreads();
        #pragma unroll
        for (int kk = 0; kk < 16; kk++) {
            float4 a = *(const float4*)&As[kk][ty * 4];
            float av[4] = {a.x, a.y, a.z, a.w};
            if (TN == 64) {
                float4 b = *(const float4*)&Bs[kk][tx * 4];
                float bv[4] = {b.x, b.y, b.z, b.w};
                #pragma unroll
                for (int m = 0; m < 4; m++)
                    #pragma unroll
                    for (int n = 0; n < 4; n++) acc[m][n] += av[m] * bv[n];
            } else {
                float4 b0 = *(const float4*)&Bs[kk][tx * 8];
                float4 b1 = *(const float4*)&Bs[kk][tx * 8 + 4];
                float bv[8] = {b0.x, b0.y, b0.z, b0.w, b1.x, b1.y, b1.z, b1.w};
                #pragma unroll
                for (int m = 0; m < 4; m++)
                    #pragma unroll
                    for (int n = 0; n < 8; n++) acc[m][n % (TN/16)] += av[m] * bv[n];
            }
        }
        __syncthreads();
    }
    #pragma unroll
    for (int m = 0; m < 4; m++) {
        size_t base = (size_t)(m0 + ty * 4 + m) * Dn + n0;
        if (TN == 64) {
            float4 o = {acc[m][0], acc[m][1], acc[m][2], acc[m][3]};
            *(float4*)&dst[base + tx * 4] = o;
        } else {
            float4 o0 = {acc[m][0], acc[m][1], acc[m][2], acc[m][3]};
            float4 o1 = {acc[m][4], acc[m][5], acc[m][6], acc[m][7]};
            *(float4*)&dst[base + tx * 8] = o0;
            *(float4*)&dst[base + tx * 8 + 4] = o1;
        }
    }
}

// ---------------------------------------------------------------------------
// Hand-rolled grid barrier. Monotonic counter per phase (no reset/generation),
// zeroed by hipMemsetAsync before launch. Agent-scope release add; acquire
// spin with short s_sleep. All NBLK blocks are co-resident by construction
// (22.5 KB LDS -> 7 blk/CU, 48 VGPR -> 8 blk/CU, capacity 1792 >> 512).
// ---------------------------------------------------------------------------
__device__ __forceinline__ void gridbar(unsigned int* bar) {
    __syncthreads();
    if (threadIdx.x == 0) {
        __threadfence();   // flush this block's prior writes device-wide
        __hip_atomic_fetch_add(bar, 1u, __ATOMIC_RELEASE, __HIP_MEMORY_SCOPE_AGENT);
        while (__hip_atomic_load(bar, __ATOMIC_ACQUIRE, __HIP_MEMORY_SCOPE_AGENT) < NBLK) {
            __builtin_amdgcn_s_sleep(2);
        }
    }
    __syncthreads();
}

// ============================================================================
// Single fused kernel: 512 blocks x 256 threads, 4 custom grid barriers.
//   P1: Wov partials (0..255), q partials (256..287), woz partials (288..319),
//       mask compaction (320..327)
//   P2: qk partials (0..63), wov = sum wp (64..319)
//   P3: token pass, one block per (sample, segment)  [all 512]
//   P4: op partials = (s/den) @ wov^T  (0..255)      [op aliases wp]
//   P5: epilogue select/sum                          (0..255)
// ============================================================================
__global__ void __launch_bounds__(256) k_fused(
    const float* __restrict__ feats, const unsigned char* __restrict__ maskbytes,
    const float* __restrict__ z, const float* __restrict__ Wq,
    const float* __restrict__ Wk, const float* __restrict__ Wv,
    const float* __restrict__ Wo, const float* __restrict__ bo,
    float* __restrict__ out,
    unsigned int* bar,
    int* nvalid, int* idx, float* qp, float* wozp, float* qkp,
    float* wov, float* sbuf, float* den, float* wp)
{
    __shared__ float As[16][68];
    __shared__ float Bs[16][132];
    __shared__ int scanbuf[256];
    __shared__ int cflags[4];
    __shared__ float sred[4 * Dn];
    __shared__ float dred[4];
    __shared__ float ssv[64];

    int tid = threadIdx.x;
    int gb = blockIdx.x;

    // --------------------------- Phase 1 ---------------------------
    if (gb < 256) {               // Wov = Wo @ Wv, Ksplit8 (K-slice 64)
        int ks = gb & 7;  int t = gb >> 3;
        int rt = t >> 2, ct = t & 3;
        gemm_tile<128, false, 1, false>(Wo, 0, rt * 64, Wv, ct * 128,
                                        ks * 64, 4, nullptr,
                                        wp + (size_t)ks * 262144, As, Bs, tid);
    } else if (gb < 288) {        // q = z @ Wq^T, Ksplit4
        int t = gb - 256; int ks = t & 3; int nt = t >> 2;
        gemm_tile<64, true, 1, false>(z, 0, 0, Wq, nt * 64,
                                      ks * 128, 8, nullptr,
                                      qp + (size_t)ks * 32768, As, Bs, tid);
    } else if (gb < 320) {        // woz = z @ Wo^T, Ksplit4
        int t = gb - 288; int ks = t & 3; int nt = t >> 2;
        gemm_tile<64, true, 1, false>(z, 0, 0, Wo, nt * 64,
                                      ks * 128, 8, nullptr,
                                      wozp + (size_t)ks * 32768, As, Bs, tid);
    } else if (gb < 328) {        // mask compaction, one block per sample
        int b = gb - 320;
        if (tid == 0) { cflags[0] = 0; cflags[1] = 0; cflags[2] = 0; }
        __syncthreads();
        int lge2 = 0, lb1 = 0, lm = 0;
        for (int p = tid; p < 4096; p += 256) {
            unsigned int v = maskbytes[p];
            if (v > 1u) lge2 = 1;
            if (v != 0u) {
                if ((p & 3) == 1) lb1 = 1;
                if ((p & 3) != 0) lm = 1;
            }
        }
        if (lge2) atomicOr(&cflags[0], 1);
        if (lb1)  atomicOr(&cflags[1], 1);
        if (lm)   atomicOr(&cflags[2], 1);
        __syncthreads();
        if (tid == 0) cflags[3] = cflags[0] ? (cflags[1] ? 2 : 4) : (cflags[2] ? 1 : 4);
        __syncthreads();
        int w = cflags[3];

        int base = tid * 16;
        int cnt = 0;
        int validbits[16];
        for (int e = 0; e < 16; e++) {
            int i = base + e;
            size_t byteoff = ((size_t)b * Nn + i) * (size_t)w;
            unsigned int nz = 0;
            for (int q = 0; q < w; q++) nz |= maskbytes[byteoff + q];
            int valid = (nz == 0) ? 1 : 0;
            validbits[e] = valid;
            cnt += valid;
        }
        scanbuf[tid] = cnt;
        __syncthreads();
        for (int off = 1; off < 256; off <<= 1) {
            int v = (tid >= off) ? scanbuf[tid - off] : 0;
            __syncthreads();
            scanbuf[tid] += v;
            __syncthreads();
        }
        int pos = scanbuf[tid] - cnt;
        for (int e = 0; e < 16; e++) {
            if (validbits[e]) { idx[b * Nn + pos] = base + e; pos++; }
        }
        if (tid == 255) nvalid[b] = scanbuf[255];
    }
    gridbar(bar + 0);

    // --------------------------- Phase 2 ---------------------------
    if (gb < 64) {                // qk partials = (sum qp) @ Wk, Ksplit8
        int ks = gb & 7; int nt = gb >> 3;
        gemm_tile<64, false, 4, false>(qp, 32768, 0, Wk, nt * 64,
                                       ks * 64, 4, nullptr,
                                       qkp + (size_t)ks * 32768, As, Bs, tid);
    } else if (gb < 320) {        // wov = sum of 8 wp partials
        int lin = (gb - 64) * 256 + tid;
        float4 v = {0.f, 0.f, 0.f, 0.f};
        #pragma unroll
        for (int p = 0; p < 8; p++) {
            float4 w = *(const float4*)&wp[(size_t)p * 262144 + (size_t)lin * 4];
            v.x += w.x; v.y += w.y; v.z += w.z; v.w += w.w;
        }
        *(float4*)&wov[(size_t)lin * 4] = v;
    }
    gridbar(bar + 1);

    // --------------------------- Phase 3: token pass ---------------------------
    {
        int wv = tid >> 6;
        int lane = tid & 63;
        int b = gb / Ln;
        int l = gb % Ln;
        int nv = nvalid[b];
        int seg_size = nv / Ln; if (seg_size < 1) seg_size = 1;
        int used = Ln * seg_size; if (used > nv) used = nv;
        int r0 = l * seg_size;
        int r1 = r0 + seg_size; if (r1 > used) r1 = used;

        float4 qa = {0.f,0.f,0.f,0.f}, qb = {0.f,0.f,0.f,0.f};
        #pragma unroll
        for (int p = 0; p < 8; p++) {
            const float4* q4 = (const float4*)(qkp + (size_t)p * 32768 +
                                               (size_t)l * Dn + lane * 8);
            float4 a = q4[0], c = q4[1];
            qa.x += a.x; qa.y += a.y; qa.z += a.z; qa.w += a.w;
            qb.x += c.x; qb.y += c.y; qb.z += c.z; qb.w += c.w;
        }
        float qf[8] = {qa.x, qa.y, qa.z, qa.w, qb.x, qb.y, qb.z, qb.w};

        float sacc[8] = {0,0,0,0,0,0,0,0};
        float dacc = 0.f;
        const float inv_d = 1.0f / (float)Dn;
        const float inv_temp = 1.0f / 22.62741699796952f;  // 1/sqrt(512)

        for (int r = r0 + wv * 2; r < r1; r += 8) {
            int has2 = (r + 1 < r1);
            int t0 = idx[b * Nn + r];
            int t1 = has2 ? idx[b * Nn + r + 1] : t0;
            const float4* p0 = (const float4*)(feats + ((size_t)b * Nn + t0) * Dn + lane * 8);
            const float4* p1 = (const float4*)(feats + ((size_t)b * Nn + t1) * Dn + lane * 8);
            float4 xa0 = p0[0], xb0 = p0[1];
            float4 xa1 = p1[0], xb1 = p1[1];
            float x0[8] = {xa0.x, xa0.y, xa0.z, xa0.w, xb0.x, xb0.y, xb0.z, xb0.w};
            float x1[8] = {xa1.x, xa1.y, xa1.z, xa1.w, xb1.x, xb1.y, xb1.z, xb1.w};
            float sum0 = 0.f, ssq0 = 0.f, sum1 = 0.f, ssq1 = 0.f;
            #pragma unroll
            for (int j = 0; j < 8; j++) {
                sum0 += x0[j]; ssq0 += x0[j] * x0[j];
                sum1 += x1[j]; ssq1 += x1[j] * x1[j];
            }
            #pragma unroll
            for (int off = 32; off > 0; off >>= 1) {
                sum0 += __shfl_xor(sum0, off);
                ssq0 += __shfl_xor(ssq0, off);
                sum1 += __shfl_xor(sum1, off);
                ssq1 += __shfl_xor(ssq1, off);
            }
            float mu0 = sum0 * inv_d, mu1 = sum1 * inv_d;
            float rstd0 = rsqrtf(ssq0 * inv_d - mu0 * mu0 + 1e-5f);
            float rstd1 = rsqrtf(ssq1 * inv_d - mu1 * mu1 + 1e-5f);
            float ln0[8], ln1[8];
            float dot0 = 0.f, dot1 = 0.f;
            #pragma unroll
            for (int j = 0; j < 8; j++) {
                ln0[j] = (x0[j] - mu0) * rstd0; dot0 += ln0[j] * qf[j];
                ln1[j] = (x1[j] - mu1) * rstd1; dot1 += ln1[j] * qf[j];
            }
            #pragma unroll
            for (int off = 32; off > 0; off >>= 1) {
                dot0 += __shfl_xor(dot0, off);
                dot1 += __shfl_xor(dot1, off);
            }
            float lg0 = fminf(5.0f, fmaxf(-5.0f, dot0 * inv_temp));
            float lg1 = fminf(5.0f, fmaxf(-5.0f, dot1 * inv_temp));
            float e0 = expf(lg0);
            float e1 = has2 ? expf(lg1) : 0.f;
            #pragma unroll
            for (int j = 0; j < 8; j++) sacc[j] += e0 * ln0[j] + e1 * ln1[j];
            dacc += e0 + e1;
        }

        #pragma unroll
        for (int j = 0; j < 8; j++) sred[wv * Dn + lane * 8 + j] = sacc[j];
        if (lane == 0) dred[wv] = dacc;
        __syncthreads();
        for (int e = tid; e < Dn; e += 256) {
            float v = sred[e] + sred[Dn + e] + sred[2 * Dn + e] + sred[3 * Dn + e];
            sbuf[(size_t)gb * Dn + e] = v;
        }
        if (tid == 0) den[gb] = dred[0] + dred[1] + dred[2] + dred[3];
    }
    gridbar(bar + 2);

    // --------------------------- Phase 4: op = (s/den) @ wov^T ---------------------------
    if (gb < 256) {
        int ks = gb & 7; int t = gb >> 3;
        int rt = t >> 2, ct = t & 3;
        int m0 = rt * 64;
        if (tid < 64) {
            float dv = den[m0 + tid];
            ssv[tid] = (dv > 0.f) ? 1.f / dv : 0.f;
        }
        __syncthreads();
        gemm_tile<128, true, 1, true>(sbuf, 0, m0, wov, ct * 128,
                                      ks * 64, 4, ssv,
                                      wp + (size_t)ks * 262144, As, Bs, tid);  // op aliases wp
    }
    gridbar(bar + 3);

    // --------------------------- Phase 5: epilogue ---------------------------
    if (gb < 256) {
        const float* op = wp;   // alias
        int lin = gb * 256 + tid;   // 65536 float4s
        int row = lin >> 7;
        int col = (lin & 127) * 4;
        int b = row >> 6, l = row & 63;
        float4 v;
        if (nvalid[b] == 0) {
            v = *(const float4*)&z[(size_t)l * Dn + col];
        } else {
            float4 bv = *(const float4*)&bo[col];
            float dv = den[row];
            if (dv > 0.f) {
                float4 a = {0.f, 0.f, 0.f, 0.f};
                #pragma unroll
                for (int p = 0; p < 8; p++) {
                    float4 w = *(const float4*)&op[(size_t)p * 262144 + (size_t)row * Dn + col];
                    a.x += w.x; a.y += w.y; a.z += w.z; a.w += w.w;
                }
                v.x = a.x + bv.x; v.y = a.y + bv.y; v.z = a.z + bv.z; v.w = a.w + bv.w;
            } else {
                float4 a = {0.f, 0.f, 0.f, 0.f};
                #pragma unroll
                for (int p = 0; p < 4; p++) {
                    float4 w = *(const float4*)&wozp[(size_t)p * 32768 + (size_t)l * Dn + col];
                    a.x += w.x; a.y += w.y; a.z += w.z; a.w += w.w;
                }
                v.x = a.x + bv.x; v.y = a.y + bv.y; v.z = a.z + bv.z; v.w = a.w + bv.w;
            }
        }
        *(float4*)&out[(size_t)row * Dn + col] = v;
    }
}

extern "C" void kernel_launch(void* const* d_in, const int* in_sizes, int n_in,
                              void* d_out, int out_size, void* d_ws, size_t ws_size,
                              hipStream_t stream) {
    const float* feats = (const float*)d_in[0];
    // d_in[1] = coords: unused by the reference
    const unsigned char* maskb = (const unsigned char*)d_in[2];
    const float* z  = (const float*)d_in[3];
    const float* Wq = (const float*)d_in[4];
    const float* Wk = (const float*)d_in[5];
    const float* Wv = (const float*)d_in[6];
    const float* Wo = (const float*)d_in[7];
    const float* bo = (const float*)d_in[8];
    float* out = (float*)d_out;

    unsigned int* bar = (unsigned int*)d_ws;   // 16 uints (4 used)
    int*   nvalid = (int*)d_ws + 16;
    int*   idx    = nvalid + 64;
    float* fbase  = (float*)(idx + Bn * Nn);
    float* qp     = fbase;                 // 4 x 32768
    float* wozp   = qp   + 4 * 32768;      // 4 x 32768
    float* qkp    = wozp + 4 * 32768;      // 8 x 32768
    float* wov    = qkp  + 8 * 32768;      // 262144
    float* sbuf   = wov  + 262144;         // 262144
    float* den    = sbuf + 262144;         // 1024 (padded)
    float* wp     = den  + 1024;           // 8 x 262144 (also op)

    hipMemsetAsync(d_ws, 0, 64, stream);   // zero barrier counters

    k_fused<<<NBLK, 256, 0, stream>>>(
        feats, maskb, z, Wq, Wk, Wv, Wo, bo, out,
        bar, nvalid, idx, qp, wozp, qkp, wov, sbuf, den, wp);
}

// Round 3
// 337.991 us; speedup vs baseline: 1.7242x; 1.4519x over previous
//
#include <hip/hip_runtime.h>
#include <math.h>

#define Bn 8
#define Nn 4096
#define Dn 512
#define Ln 64
#define NBLK 512

// ---------------------------------------------------------------------------
// Shared-memory-tiled fp32 GEMM building block (unchanged, verified).
//   C_tile(64 x TN) += A[m0.., kbase..kbase+16*ksteps) @ Beff
//   BT=false: Beff[k][n] = B[k*512 + n];  BT=true: Beff[k][n] = B[n*512 + k]
//   NPART>1: A is NPART partials (stride apstride) summed during staging.
//   SCALE: multiply A row r by sv[r] during staging.
// 256 threads, micro-tile 4 x (TN/16).
// ---------------------------------------------------------------------------
template<int TN, bool BT, int NPART, bool SCALE>
__device__ __forceinline__ void gemm_tile(
    const float* A, size_t apstride, int m0,
    const float* B, int n0, int kbase, int ksteps,
    const float* sv,
    float* dst,
    float (*As)[68], float (*Bs)[132], int tid)
{
    const int ty = tid >> 4;
    const int tx = tid & 15;
    float acc[4][TN / 16];
    #pragma unroll
    for (int m = 0; m < 4; m++)
        #pragma unroll
        for (int n = 0; n < TN / 16; n++) acc[m][n] = 0.f;

    for (int s = 0; s < ksteps; s++) {
        const int k0 = kbase + s * 16;
        {
            int r = tid >> 2, kq = tid & 3;
            float4 v = *(const float4*)&A[(size_t)(m0 + r) * Dn + k0 + kq * 4];
            #pragma unroll
            for (int p = 1; p < NPART; p++) {
                float4 w = *(const float4*)&A[(size_t)p * apstride +
                                              (size_t)(m0 + r) * Dn + k0 + kq * 4];
                v.x += w.x; v.y += w.y; v.z += w.z; v.w += w.w;
            }
            if (SCALE) { float sc = sv[r]; v.x *= sc; v.y *= sc; v.z *= sc; v.w *= sc; }
            As[kq * 4 + 0][r] = v.x;
            As[kq * 4 + 1][r] = v.y;
            As[kq * 4 + 2][r] = v.z;
            As[kq * 4 + 3][r] = v.w;
        }
        #pragma unroll
        for (int rep = 0; rep < TN / 64; rep++) {
            int lin = tid + rep * 256;
            if (!BT) {
                int kk = lin / (TN / 4), jq = lin % (TN / 4);
                *(float4*)&Bs[kk][jq * 4] =
                    *(const float4*)&B[(size_t)(k0 + kk) * Dn + n0 + jq * 4];
            } else {
                int j = lin >> 2, kq = lin & 3;
                float4 v = *(const float4*)&B[(size_t)(n0 + j) * Dn + k0 + kq * 4];
                Bs[kq * 4 + 0][j] = v.x;
                Bs[kq * 4 + 1][j] = v.y;
                Bs[kq * 4 + 2][j] = v.z;
                Bs[kq * 4 + 3][j] = v.w;
            }
        }
        __syncthreads();
        #pragma unroll
        for (int kk = 0; kk < 16; kk++) {
            float4 a = *(const float4*)&As[kk][ty * 4];
            float av[4] = {a.x, a.y, a.z, a.w};
            if (TN == 64) {
                float4 b = *(const float4*)&Bs[kk][tx * 4];
                float bv[4] = {b.x, b.y, b.z, b.w};
                #pragma unroll
                for (int m = 0; m < 4; m++)
                    #pragma unroll
                    for (int n = 0; n < 4; n++) acc[m][n] += av[m] * bv[n];
            } else {
                float4 b0 = *(const float4*)&Bs[kk][tx * 8];
                float4 b1 = *(const float4*)&Bs[kk][tx * 8 + 4];
                float bv[8] = {b0.x, b0.y, b0.z, b0.w, b1.x, b1.y, b1.z, b1.w};
                #pragma unroll
                for (int m = 0; m < 4; m++)
                    #pragma unroll
                    for (int n = 0; n < 8; n++) acc[m][n % (TN/16)] += av[m] * bv[n];
            }
        }
        __syncthreads();
    }
    #pragma unroll
    for (int m = 0; m < 4; m++) {
        size_t base = (size_t)(m0 + ty * 4 + m) * Dn + n0;
        if (TN == 64) {
            float4 o = {acc[m][0], acc[m][1], acc[m][2], acc[m][3]};
            *(float4*)&dst[base + tx * 4] = o;
        } else {
            float4 o0 = {acc[m][0], acc[m][1], acc[m][2], acc[m][3]};
            float4 o1 = {acc[m][4], acc[m][5], acc[m][6], acc[m][7]};
            *(float4*)&dst[base + tx * 8] = o0;
            *(float4*)&dst[base + tx * 8 + 4] = o1;
        }
    }
}

// ---------------------------------------------------------------------------
// Grid barrier, v2. Round-2 post-mortem: acquire-load in the poll loop emitted
// a buffer_inv (full L1/L2 invalidate) EVERY poll -> ~90us/barrier and starved
// the phases. Fix: RELAXED polls (plain coherent load, no cache ops), exactly
// ONE release fence before the add and ONE acquire fence after spin exit.
// s_sleep(16) ~ 1024 cyc poll interval keeps same-line MALL pressure low.
// Monotonic counter per phase, zeroed by hipMemsetAsync before launch.
// All NBLK blocks co-resident (22.5 KB LDS -> 7 blk/CU; 512 = 2 blk/CU).
// ---------------------------------------------------------------------------
__device__ __forceinline__ void gridbar(unsigned int* bar) {
    __syncthreads();
    if (threadIdx.x == 0) {
        __threadfence();   // release: one L2 writeback so other XCDs see our writes
        __hip_atomic_fetch_add(bar, 1u, __ATOMIC_RELAXED, __HIP_MEMORY_SCOPE_AGENT);
        while (__hip_atomic_load(bar, __ATOMIC_RELAXED, __HIP_MEMORY_SCOPE_AGENT) < NBLK) {
            __builtin_amdgcn_s_sleep(16);
        }
        __threadfence();   // acquire: one invalidate so we see other XCDs' writes
    }
    __syncthreads();
}

// ============================================================================
// Single fused kernel: 512 blocks x 256 threads, 4 custom grid barriers.
//   P1: Wov partials (0..255), q partials (256..287), woz partials (288..319),
//       mask compaction (320..327)
//   P2: qk partials (0..63), wov = sum wp (64..319)
//   P3: token pass, one block per (sample, segment)  [all 512]
//   P4: op partials = (s/den) @ wov^T  (0..255)      [op aliases wp]
//   P5: epilogue select/sum                          (0..255)
// ============================================================================
__global__ void __launch_bounds__(256) k_fused(
    const float* __restrict__ feats, const unsigned char* __restrict__ maskbytes,
    const float* __restrict__ z, const float* __restrict__ Wq,
    const float* __restrict__ Wk, const float* __restrict__ Wv,
    const float* __restrict__ Wo, const float* __restrict__ bo,
    float* __restrict__ out,
    unsigned int* bar,
    int* nvalid, int* idx, float* qp, float* wozp, float* qkp,
    float* wov, float* sbuf, float* den, float* wp)
{
    __shared__ float As[16][68];
    __shared__ float Bs[16][132];
    __shared__ int scanbuf[256];
    __shared__ int cflags[4];
    __shared__ float sred[4 * Dn];
    __shared__ float dred[4];
    __shared__ float ssv[64];

    int tid = threadIdx.x;
    int gb = blockIdx.x;

    // --------------------------- Phase 1 ---------------------------
    if (gb < 256) {               // Wov = Wo @ Wv, Ksplit8 (K-slice 64)
        int ks = gb & 7;  int t = gb >> 3;
        int rt = t >> 2, ct = t & 3;
        gemm_tile<128, false, 1, false>(Wo, 0, rt * 64, Wv, ct * 128,
                                        ks * 64, 4, nullptr,
                                        wp + (size_t)ks * 262144, As, Bs, tid);
    } else if (gb < 288) {        // q = z @ Wq^T, Ksplit4
        int t = gb - 256; int ks = t & 3; int nt = t >> 2;
        gemm_tile<64, true, 1, false>(z, 0, 0, Wq, nt * 64,
                                      ks * 128, 8, nullptr,
                                      qp + (size_t)ks * 32768, As, Bs, tid);
    } else if (gb < 320) {        // woz = z @ Wo^T, Ksplit4
        int t = gb - 288; int ks = t & 3; int nt = t >> 2;
        gemm_tile<64, true, 1, false>(z, 0, 0, Wo, nt * 64,
                                      ks * 128, 8, nullptr,
                                      wozp + (size_t)ks * 32768, As, Bs, tid);
    } else if (gb < 328) {        // mask compaction, one block per sample
        int b = gb - 320;
        if (tid == 0) { cflags[0] = 0; cflags[1] = 0; cflags[2] = 0; }
        __syncthreads();
        int lge2 = 0, lb1 = 0, lm = 0;
        for (int p = tid; p < 4096; p += 256) {
            unsigned int v = maskbytes[p];
            if (v > 1u) lge2 = 1;
            if (v != 0u) {
                if ((p & 3) == 1) lb1 = 1;
                if ((p & 3) != 0) lm = 1;
            }
        }
        if (lge2) atomicOr(&cflags[0], 1);
        if (lb1)  atomicOr(&cflags[1], 1);
        if (lm)   atomicOr(&cflags[2], 1);
        __syncthreads();
        if (tid == 0) cflags[3] = cflags[0] ? (cflags[1] ? 2 : 4) : (cflags[2] ? 1 : 4);
        __syncthreads();
        int w = cflags[3];

        int base = tid * 16;
        int cnt = 0;
        int validbits[16];
        for (int e = 0; e < 16; e++) {
            int i = base + e;
            size_t byteoff = ((size_t)b * Nn + i) * (size_t)w;
            unsigned int nz = 0;
            for (int q = 0; q < w; q++) nz |= maskbytes[byteoff + q];
            int valid = (nz == 0) ? 1 : 0;
            validbits[e] = valid;
            cnt += valid;
        }
        scanbuf[tid] = cnt;
        __syncthreads();
        for (int off = 1; off < 256; off <<= 1) {
            int v = (tid >= off) ? scanbuf[tid - off] : 0;
            __syncthreads();
            scanbuf[tid] += v;
            __syncthreads();
        }
        int pos = scanbuf[tid] - cnt;
        for (int e = 0; e < 16; e++) {
            if (validbits[e]) { idx[b * Nn + pos] = base + e; pos++; }
        }
        if (tid == 255) nvalid[b] = scanbuf[255];
    }
    gridbar(bar + 0);

    // --------------------------- Phase 2 ---------------------------
    if (gb < 64) {                // qk partials = (sum qp) @ Wk, Ksplit8
        int ks = gb & 7; int nt = gb >> 3;
        gemm_tile<64, false, 4, false>(qp, 32768, 0, Wk, nt * 64,
                                       ks * 64, 4, nullptr,
                                       qkp + (size_t)ks * 32768, As, Bs, tid);
    } else if (gb < 320) {        // wov = sum of 8 wp partials
        int lin = (gb - 64) * 256 + tid;
        float4 v = {0.f, 0.f, 0.f, 0.f};
        #pragma unroll
        for (int p = 0; p < 8; p++) {
            float4 w = *(const float4*)&wp[(size_t)p * 262144 + (size_t)lin * 4];
            v.x += w.x; v.y += w.y; v.z += w.z; v.w += w.w;
        }
        *(float4*)&wov[(size_t)lin * 4] = v;
    }
    gridbar(bar + 1);

    // --------------------------- Phase 3: token pass ---------------------------
    {
        int wv = tid >> 6;
        int lane = tid & 63;
        int b = gb / Ln;
        int l = gb % Ln;
        int nv = nvalid[b];
        int seg_size = nv / Ln; if (seg_size < 1) seg_size = 1;
        int used = Ln * seg_size; if (used > nv) used = nv;
        int r0 = l * seg_size;
        int r1 = r0 + seg_size; if (r1 > used) r1 = used;

        float4 qa = {0.f,0.f,0.f,0.f}, qb = {0.f,0.f,0.f,0.f};
        #pragma unroll
        for (int p = 0; p < 8; p++) {
            const float4* q4 = (const float4*)(qkp + (size_t)p * 32768 +
                                               (size_t)l * Dn + lane * 8);
            float4 a = q4[0], c = q4[1];
            qa.x += a.x; qa.y += a.y; qa.z += a.z; qa.w += a.w;
            qb.x += c.x; qb.y += c.y; qb.z += c.z; qb.w += c.w;
        }
        float qf[8] = {qa.x, qa.y, qa.z, qa.w, qb.x, qb.y, qb.z, qb.w};

        float sacc[8] = {0,0,0,0,0,0,0,0};
        float dacc = 0.f;
        const float inv_d = 1.0f / (float)Dn;
        const float inv_temp = 1.0f / 22.62741699796952f;  // 1/sqrt(512)

        for (int r = r0 + wv * 2; r < r1; r += 8) {
            int has2 = (r + 1 < r1);
            int t0 = idx[b * Nn + r];
            int t1 = has2 ? idx[b * Nn + r + 1] : t0;
            const float4* p0 = (const float4*)(feats + ((size_t)b * Nn + t0) * Dn + lane * 8);
            const float4* p1 = (const float4*)(feats + ((size_t)b * Nn + t1) * Dn + lane * 8);
            float4 xa0 = p0[0], xb0 = p0[1];
            float4 xa1 = p1[0], xb1 = p1[1];
            float x0[8] = {xa0.x, xa0.y, xa0.z, xa0.w, xb0.x, xb0.y, xb0.z, xb0.w};
            float x1[8] = {xa1.x, xa1.y, xa1.z, xa1.w, xb1.x, xb1.y, xb1.z, xb1.w};
            float sum0 = 0.f, ssq0 = 0.f, sum1 = 0.f, ssq1 = 0.f;
            #pragma unroll
            for (int j = 0; j < 8; j++) {
                sum0 += x0[j]; ssq0 += x0[j] * x0[j];
                sum1 += x1[j]; ssq1 += x1[j] * x1[j];
            }
            #pragma unroll
            for (int off = 32; off > 0; off >>= 1) {
                sum0 += __shfl_xor(sum0, off);
                ssq0 += __shfl_xor(ssq0, off);
                sum1 += __shfl_xor(sum1, off);
                ssq1 += __shfl_xor(ssq1, off);
            }
            float mu0 = sum0 * inv_d, mu1 = sum1 * inv_d;
            float rstd0 = rsqrtf(ssq0 * inv_d - mu0 * mu0 + 1e-5f);
            float rstd1 = rsqrtf(ssq1 * inv_d - mu1 * mu1 + 1e-5f);
            float ln0[8], ln1[8];
            float dot0 = 0.f, dot1 = 0.f;
            #pragma unroll
            for (int j = 0; j < 8; j++) {
                ln0[j] = (x0[j] - mu0) * rstd0; dot0 += ln0[j] * qf[j];
                ln1[j] = (x1[j] - mu1) * rstd1; dot1 += ln1[j] * qf[j];
            }
            #pragma unroll
            for (int off = 32; off > 0; off >>= 1) {
                dot0 += __shfl_xor(dot0, off);
                dot1 += __shfl_xor(dot1, off);
            }
            float lg0 = fminf(5.0f, fmaxf(-5.0f, dot0 * inv_temp));
            float lg1 = fminf(5.0f, fmaxf(-5.0f, dot1 * inv_temp));
            float e0 = expf(lg0);
            float e1 = has2 ? expf(lg1) : 0.f;
            #pragma unroll
            for (int j = 0; j < 8; j++) sacc[j] += e0 * ln0[j] + e1 * ln1[j];
            dacc += e0 + e1;
        }

        #pragma unroll
        for (int j = 0; j < 8; j++) sred[wv * Dn + lane * 8 + j] = sacc[j];
        if (lane == 0) dred[wv] = dacc;
        __syncthreads();
        for (int e = tid; e < Dn; e += 256) {
            float v = sred[e] + sred[Dn + e] + sred[2 * Dn + e] + sred[3 * Dn + e];
            sbuf[(size_t)gb * Dn + e] = v;
        }
        if (tid == 0) den[gb] = dred[0] + dred[1] + dred[2] + dred[3];
    }
    gridbar(bar + 2);

    // --------------------------- Phase 4: op = (s/den) @ wov^T ---------------------------
    if (gb < 256) {
        int ks = gb & 7; int t = gb >> 3;
        int rt = t >> 2, ct = t & 3;
        int m0 = rt * 64;
        if (tid < 64) {
            float dv = den[m0 + tid];
            ssv[tid] = (dv > 0.f) ? 1.f / dv : 0.f;
        }
        __syncthreads();
        gemm_tile<128, true, 1, true>(sbuf, 0, m0, wov, ct * 128,
                                      ks * 64, 4, ssv,
                                      wp + (size_t)ks * 262144, As, Bs, tid);  // op aliases wp
    }
    gridbar(bar + 3);

    // --------------------------- Phase 5: epilogue ---------------------------
    if (gb < 256) {
        const float* op = wp;   // alias
        int lin = gb * 256 + tid;   // 65536 float4s
        int row = lin >> 7;
        int col = (lin & 127) * 4;
        int b = row >> 6, l = row & 63;
        float4 v;
        if (nvalid[b] == 0) {
            v = *(const float4*)&z[(size_t)l * Dn + col];
        } else {
            float4 bv = *(const float4*)&bo[col];
            float dv = den[row];
            if (dv > 0.f) {
                float4 a = {0.f, 0.f, 0.f, 0.f};
                #pragma unroll
                for (int p = 0; p < 8; p++) {
                    float4 w = *(const float4*)&op[(size_t)p * 262144 + (size_t)row * Dn + col];
                    a.x += w.x; a.y += w.y; a.z += w.z; a.w += w.w;
                }
                v.x = a.x + bv.x; v.y = a.y + bv.y; v.z = a.z + bv.z; v.w = a.w + bv.w;
            } else {
                float4 a = {0.f, 0.f, 0.f, 0.f};
                #pragma unroll
                for (int p = 0; p < 4; p++) {
                    float4 w = *(const float4*)&wozp[(size_t)p * 32768 + (size_t)l * Dn + col];
                    a.x += w.x; a.y += w.y; a.z += w.z; a.w += w.w;
                }
                v.x = a.x + bv.x; v.y = a.y + bv.y; v.z = a.z + bv.z; v.w = a.w + bv.w;
            }
        }
        *(float4*)&out[(size_t)row * Dn + col] = v;
    }
}

extern "C" void kernel_launch(void* const* d_in, const int* in_sizes, int n_in,
                              void* d_out, int out_size, void* d_ws, size_t ws_size,
                              hipStream_t stream) {
    const float* feats = (const float*)d_in[0];
    // d_in[1] = coords: unused by the reference
    const unsigned char* maskb = (const unsigned char*)d_in[2];
    const float* z  = (const float*)d_in[3];
    const float* Wq = (const float*)d_in[4];
    const float* Wk = (const float*)d_in[5];
    const float* Wv = (const float*)d_in[6];
    const float* Wo = (const float*)d_in[7];
    const float* bo = (const float*)d_in[8];
    float* out = (float*)d_out;

    unsigned int* bar = (unsigned int*)d_ws;   // 16 uints (4 used)
    int*   nvalid = (int*)d_ws + 16;
    int*   idx    = nvalid + 64;
    float* fbase  = (float*)(idx + Bn * Nn);
    float* qp     = fbase;                 // 4 x 32768
    float* wozp   = qp   + 4 * 32768;      // 4 x 32768
    float* qkp    = wozp + 4 * 32768;      // 8 x 32768
    float* wov    = qkp  + 8 * 32768;      // 262144
    float* sbuf   = wov  + 262144;         // 262144
    float* den    = sbuf + 262144;         // 1024 (padded)
    float* wp     = den  + 1024;           // 8 x 262144 (also op)

    hipMemsetAsync(d_ws, 0, 64, stream);   // zero barrier counters

    k_fused<<<NBLK, 256, 0, stream>>>(
        feats, maskb, z, Wq, Wk, Wv, Wo, bo, out,
        bar, nvalid, idx, qp, wozp, qkp, wov, sbuf, den, wp);
}

// Round 4
// 216.509 us; speedup vs baseline: 2.6917x; 1.5611x over previous
//
#include <hip/hip_runtime.h>
#include <math.h>

#define Bn 8
#define Nn 4096
#define Dn 512
#define Ln 64
#define NBLK 512

// ---------------------------------------------------------------------------
// Shared-memory-tiled fp32 GEMM building block (verified core, + EPI variant).
//   C_tile(64 x TN) += A[m0.., kbase..kbase+16*ksteps) @ Beff
//   BT=false: Beff[k][n] = B[k*512 + n];  BT=true: Beff[k][n] = B[n*512 + k]
//   NPART>1: A is NPART partials (stride apstride) summed during staging.
//   SCALE: multiply A row r by sv[r] during staging.
//   EPI (TN=64 only): fused epilogue — per output row:
//     nvalid[b]==0 -> z[l]; den[row]>0 -> acc+bo; else -> woz[l]+bo.
// 256 threads, micro-tile 4 x (TN/16).
// ---------------------------------------------------------------------------
template<int TN, bool BT, int NPART, bool SCALE, bool EPI = false>
__device__ __forceinline__ void gemm_tile(
    const float* A, size_t apstride, int m0,
    const float* B, int n0, int kbase, int ksteps,
    const float* sv,
    float* dst,
    float (*As)[68], float (*Bs)[132], int tid,
    const float* eden = nullptr, const int* env = nullptr,
    const float* ez = nullptr, const float* ewoz = nullptr,
    const float* ebo = nullptr)
{
    static_assert(!EPI || TN == 64, "EPI only for TN=64");
    const int ty = tid >> 4;
    const int tx = tid & 15;
    float acc[4][TN / 16];
    #pragma unroll
    for (int m = 0; m < 4; m++)
        #pragma unroll
        for (int n = 0; n < TN / 16; n++) acc[m][n] = 0.f;

    for (int s = 0; s < ksteps; s++) {
        const int k0 = kbase + s * 16;
        {
            int r = tid >> 2, kq = tid & 3;
            float4 v = *(const float4*)&A[(size_t)(m0 + r) * Dn + k0 + kq * 4];
            #pragma unroll
            for (int p = 1; p < NPART; p++) {
                float4 w = *(const float4*)&A[(size_t)p * apstride +
                                              (size_t)(m0 + r) * Dn + k0 + kq * 4];
                v.x += w.x; v.y += w.y; v.z += w.z; v.w += w.w;
            }
            if (SCALE) { float sc = sv[r]; v.x *= sc; v.y *= sc; v.z *= sc; v.w *= sc; }
            As[kq * 4 + 0][r] = v.x;
            As[kq * 4 + 1][r] = v.y;
            As[kq * 4 + 2][r] = v.z;
            As[kq * 4 + 3][r] = v.w;
        }
        #pragma unroll
        for (int rep = 0; rep < TN / 64; rep++) {
            int lin = tid + rep * 256;
            if (!BT) {
                int kk = lin / (TN / 4), jq = lin % (TN / 4);
                *(float4*)&Bs[kk][jq * 4] =
                    *(const float4*)&B[(size_t)(k0 + kk) * Dn + n0 + jq * 4];
            } else {
                int j = lin >> 2, kq = lin & 3;
                float4 v = *(const float4*)&B[(size_t)(n0 + j) * Dn + k0 + kq * 4];
                Bs[kq * 4 + 0][j] = v.x;
                Bs[kq * 4 + 1][j] = v.y;
                Bs[kq * 4 + 2][j] = v.z;
                Bs[kq * 4 + 3][j] = v.w;
            }
        }
        __syncthreads();
        #pragma unroll
        for (int kk = 0; kk < 16; kk++) {
            float4 a = *(const float4*)&As[kk][ty * 4];
            float av[4] = {a.x, a.y, a.z, a.w};
            if (TN == 64) {
                float4 b = *(const float4*)&Bs[kk][tx * 4];
                float bv[4] = {b.x, b.y, b.z, b.w};
                #pragma unroll
                for (int m = 0; m < 4; m++)
                    #pragma unroll
                    for (int n = 0; n < 4; n++) acc[m][n] += av[m] * bv[n];
            } else {
                float4 b0 = *(const float4*)&Bs[kk][tx * 8];
                float4 b1 = *(const float4*)&Bs[kk][tx * 8 + 4];
                float bv[8] = {b0.x, b0.y, b0.z, b0.w, b1.x, b1.y, b1.z, b1.w};
                #pragma unroll
                for (int m = 0; m < 4; m++)
                    #pragma unroll
                    for (int n = 0; n < 8; n++) acc[m][n % (TN/16)] += av[m] * bv[n];
            }
        }
        __syncthreads();
    }
    // ---- write tile ----
    if constexpr (EPI) {
        int col = n0 + tx * 4;
        float4 bv = *(const float4*)&ebo[col];
        #pragma unroll
        for (int m = 0; m < 4; m++) {
            int row = m0 + ty * 4 + m;
            int bb = row >> 6, ll = row & 63;
            float4 v;
            if (env[bb] == 0) {
                v = *(const float4*)&ez[(size_t)ll * Dn + col];
            } else if (eden[row] > 0.f) {
                v.x = acc[m][0] + bv.x; v.y = acc[m][1] + bv.y;
                v.z = acc[m][2] + bv.z; v.w = acc[m][3] + bv.w;
            } else {
                float4 wz = *(const float4*)&ewoz[(size_t)ll * Dn + col];
                v.x = wz.x + bv.x; v.y = wz.y + bv.y;
                v.z = wz.z + bv.z; v.w = wz.w + bv.w;
            }
            *(float4*)&dst[(size_t)row * Dn + col] = v;
        }
    } else {
        #pragma unroll
        for (int m = 0; m < 4; m++) {
            size_t base = (size_t)(m0 + ty * 4 + m) * Dn + n0;
            if (TN == 64) {
                float4 o = {acc[m][0], acc[m][1], acc[m][2], acc[m][3]};
                *(float4*)&dst[base + tx * 4] = o;
            } else {
                float4 o0 = {acc[m][0], acc[m][1], acc[m][2], acc[m][3]};
                float4 o1 = {acc[m][4], acc[m][5], acc[m][6], acc[m][7]};
                *(float4*)&dst[base + tx * 8] = o0;
                *(float4*)&dst[base + tx * 8 + 4] = o1;
            }
        }
    }
}

// ---------------------------------------------------------------------------
// Producer->consumer flags, v3. Round-3 post-mortem: agent-scope relaxed polls
// are served STALE by the local (non-cross-coherent) XCD L2; spin exit waited
// on random eviction (~50us). Fix: SYSTEM-scope relaxed atomics for both the
// arrive-add and the poll-load — both execute at the coherent point (MALL),
// staleness impossible, and relaxed => no per-poll cache maintenance ops.
// Data visibility: __threadfence (agent) once per signal (wbl2) / once per
// wait-exit (inv) — the pattern rounds 2-3 proved correct.
// Counters live in the (now unused) wp region, 128B apart, memset to 0.
// ---------------------------------------------------------------------------
#define CTR_CMP   0     // -> 8
#define CTR_Q     32    // -> 32
#define CTR_QK    64    // -> 64
#define CTR_WOV   96    // -> 64
#define CTR_WOZ   128   // -> 8
#define CTR_TOK   160   // -> 512

__device__ __forceinline__ void wait_ctr(unsigned int* p, unsigned int tgt) {
    if (threadIdx.x == 0) {
        while (__hip_atomic_load(p, __ATOMIC_RELAXED, __HIP_MEMORY_SCOPE_SYSTEM) < tgt)
            __builtin_amdgcn_s_sleep(16);
        __threadfence();   // acquire: invalidate local caches once
    }
    __syncthreads();
}

__device__ __forceinline__ void signal_ctr(unsigned int* p) {
    __syncthreads();       // all block stores issued & drained (vmcnt 0 at barrier)
    if (threadIdx.x == 0) {
        __threadfence();   // release: write back L2 once
        __hip_atomic_fetch_add(p, 1u, __ATOMIC_RELAXED, __HIP_MEMORY_SCOPE_SYSTEM);
    }
}

// ============================================================================
// Single fused kernel, flag-DAG schedule (no grid barriers). 512 x 256.
//   roles: 64..95  q   = z@Wq^T   (Ksplit4, verbatim-verified call)
//          96..159 qk  = q@Wk     (Ksplit8, waits q_done)
//          160..223 wov = Wo@Wv   (direct K=512, 64x64 tiles)
//          224..231 woz = z@Wo^T  (direct K=512)
//          232..239 mask compaction
//   all:   token pass (waits cmp_done, qk_done)
//   0..63: out tile = (s/den)@wov^T + fused epilogue (waits tok/wov/woz)
// ============================================================================
__global__ void __launch_bounds__(256) k_fused(
    const float* __restrict__ feats, const unsigned char* __restrict__ maskbytes,
    const float* __restrict__ z, const float* __restrict__ Wq,
    const float* __restrict__ Wk, const float* __restrict__ Wv,
    const float* __restrict__ Wo, const float* __restrict__ bo,
    float* __restrict__ out,
    unsigned int* ctr,
    int* nvalid, int* idx, float* qp, float* woz, float* qkp,
    float* wov, float* sbuf, float* den)
{
    __shared__ float As[16][68];
    __shared__ float Bs[16][132];
    __shared__ int scanbuf[256];
    __shared__ int cflags[4];
    __shared__ float sred[4 * Dn];
    __shared__ float dred[4];
    __shared__ float ssv[64];

    int tid = threadIdx.x;
    int gb = blockIdx.x;

    // --------------------------- producer roles ---------------------------
    if (gb >= 64 && gb < 96) {            // q = z @ Wq^T, Ksplit4
        int t = gb - 64; int ks = t & 3; int nt = t >> 2;
        gemm_tile<64, true, 1, false>(z, 0, 0, Wq, nt * 64,
                                      ks * 128, 8, nullptr,
                                      qp + (size_t)ks * 32768, As, Bs, tid);
        signal_ctr(ctr + CTR_Q);
    } else if (gb >= 96 && gb < 160) {    // qk = (sum qp) @ Wk, Ksplit8
        wait_ctr(ctr + CTR_Q, 32);
        int t = gb - 96; int ks = t & 7; int nt = t >> 3;
        gemm_tile<64, false, 4, false>(qp, 32768, 0, Wk, nt * 64,
                                       ks * 64, 4, nullptr,
                                       qkp + (size_t)ks * 32768, As, Bs, tid);
        signal_ctr(ctr + CTR_QK);
    } else if (gb >= 160 && gb < 224) {   // wov = Wo @ Wv, direct K=512
        int t = gb - 160; int rt = t >> 3; int ct = t & 7;
        gemm_tile<64, false, 1, false>(Wo, 0, rt * 64, Wv, ct * 64,
                                       0, 32, nullptr, wov, As, Bs, tid);
        signal_ctr(ctr + CTR_WOV);
    } else if (gb >= 224 && gb < 232) {   // woz = z @ Wo^T, direct K=512
        int nt = gb - 224;
        gemm_tile<64, true, 1, false>(z, 0, 0, Wo, nt * 64,
                                      0, 32, nullptr, woz, As, Bs, tid);
        signal_ctr(ctr + CTR_WOZ);
    } else if (gb >= 232 && gb < 240) {   // mask compaction, one block/sample
        int b = gb - 232;
        if (tid == 0) { cflags[0] = 0; cflags[1] = 0; cflags[2] = 0; }
        __syncthreads();
        int lge2 = 0, lb1 = 0, lm = 0;
        for (int p = tid; p < 4096; p += 256) {
            unsigned int v = maskbytes[p];
            if (v > 1u) lge2 = 1;
            if (v != 0u) {
                if ((p & 3) == 1) lb1 = 1;
                if ((p & 3) != 0) lm = 1;
            }
        }
        if (lge2) atomicOr(&cflags[0], 1);
        if (lb1)  atomicOr(&cflags[1], 1);
        if (lm)   atomicOr(&cflags[2], 1);
        __syncthreads();
        if (tid == 0) cflags[3] = cflags[0] ? (cflags[1] ? 2 : 4) : (cflags[2] ? 1 : 4);
        __syncthreads();
        int w = cflags[3];

        int base = tid * 16;
        int cnt = 0;
        int validbits[16];
        for (int e = 0; e < 16; e++) {
            int i = base + e;
            size_t byteoff = ((size_t)b * Nn + i) * (size_t)w;
            unsigned int nz = 0;
            for (int q = 0; q < w; q++) nz |= maskbytes[byteoff + q];
            int valid = (nz == 0) ? 1 : 0;
            validbits[e] = valid;
            cnt += valid;
        }
        scanbuf[tid] = cnt;
        __syncthreads();
        for (int off = 1; off < 256; off <<= 1) {
            int v = (tid >= off) ? scanbuf[tid - off] : 0;
            __syncthreads();
            scanbuf[tid] += v;
            __syncthreads();
        }
        int pos = scanbuf[tid] - cnt;
        for (int e = 0; e < 16; e++) {
            if (validbits[e]) { idx[b * Nn + pos] = base + e; pos++; }
        }
        if (tid == 255) nvalid[b] = scanbuf[255];
        signal_ctr(ctr + CTR_CMP);
    }

    // --------------------------- token pass (all blocks) ---------------------------
    wait_ctr(ctr + CTR_CMP, 8);
    wait_ctr(ctr + CTR_QK, 64);
    {
        int wv = tid >> 6;
        int lane = tid & 63;
        int b = gb / Ln;
        int l = gb % Ln;
        int nv = nvalid[b];
        int seg_size = nv / Ln; if (seg_size < 1) seg_size = 1;
        int used = Ln * seg_size; if (used > nv) used = nv;
        int r0 = l * seg_size;
        int r1 = r0 + seg_size; if (r1 > used) r1 = used;

        float4 qa = {0.f,0.f,0.f,0.f}, qb = {0.f,0.f,0.f,0.f};
        #pragma unroll
        for (int p = 0; p < 8; p++) {
            const float4* q4 = (const float4*)(qkp + (size_t)p * 32768 +
                                               (size_t)l * Dn + lane * 8);
            float4 a = q4[0], c = q4[1];
            qa.x += a.x; qa.y += a.y; qa.z += a.z; qa.w += a.w;
            qb.x += c.x; qb.y += c.y; qb.z += c.z; qb.w += c.w;
        }
        float qf[8] = {qa.x, qa.y, qa.z, qa.w, qb.x, qb.y, qb.z, qb.w};

        float sacc[8] = {0,0,0,0,0,0,0,0};
        float dacc = 0.f;
        const float inv_d = 1.0f / (float)Dn;
        const float inv_temp = 1.0f / 22.62741699796952f;  // 1/sqrt(512)

        for (int r = r0 + wv * 2; r < r1; r += 8) {
            int has2 = (r + 1 < r1);
            int t0 = idx[b * Nn + r];
            int t1 = has2 ? idx[b * Nn + r + 1] : t0;
            const float4* p0 = (const float4*)(feats + ((size_t)b * Nn + t0) * Dn + lane * 8);
            const float4* p1 = (const float4*)(feats + ((size_t)b * Nn + t1) * Dn + lane * 8);
            float4 xa0 = p0[0], xb0 = p0[1];
            float4 xa1 = p1[0], xb1 = p1[1];
            float x0[8] = {xa0.x, xa0.y, xa0.z, xa0.w, xb0.x, xb0.y, xb0.z, xb0.w};
            float x1[8] = {xa1.x, xa1.y, xa1.z, xa1.w, xb1.x, xb1.y, xb1.z, xb1.w};
            float sum0 = 0.f, ssq0 = 0.f, sum1 = 0.f, ssq1 = 0.f;
            #pragma unroll
            for (int j = 0; j < 8; j++) {
                sum0 += x0[j]; ssq0 += x0[j] * x0[j];
                sum1 += x1[j]; ssq1 += x1[j] * x1[j];
            }
            #pragma unroll
            for (int off = 32; off > 0; off >>= 1) {
                sum0 += __shfl_xor(sum0, off);
                ssq0 += __shfl_xor(ssq0, off);
                sum1 += __shfl_xor(sum1, off);
                ssq1 += __shfl_xor(ssq1, off);
            }
            float mu0 = sum0 * inv_d, mu1 = sum1 * inv_d;
            float rstd0 = rsqrtf(ssq0 * inv_d - mu0 * mu0 + 1e-5f);
            float rstd1 = rsqrtf(ssq1 * inv_d - mu1 * mu1 + 1e-5f);
            float ln0[8], ln1[8];
            float dot0 = 0.f, dot1 = 0.f;
            #pragma unroll
            for (int j = 0; j < 8; j++) {
                ln0[j] = (x0[j] - mu0) * rstd0; dot0 += ln0[j] * qf[j];
                ln1[j] = (x1[j] - mu1) * rstd1; dot1 += ln1[j] * qf[j];
            }
            #pragma unroll
            for (int off = 32; off > 0; off >>= 1) {
                dot0 += __shfl_xor(dot0, off);
                dot1 += __shfl_xor(dot1, off);
            }
            float lg0 = fminf(5.0f, fmaxf(-5.0f, dot0 * inv_temp));
            float lg1 = fminf(5.0f, fmaxf(-5.0f, dot1 * inv_temp));
            float e0 = expf(lg0);
            float e1 = has2 ? expf(lg1) : 0.f;
            #pragma unroll
            for (int j = 0; j < 8; j++) sacc[j] += e0 * ln0[j] + e1 * ln1[j];
            dacc += e0 + e1;
        }

        #pragma unroll
        for (int j = 0; j < 8; j++) sred[wv * Dn + lane * 8 + j] = sacc[j];
        if (lane == 0) dred[wv] = dacc;
        __syncthreads();
        for (int e = tid; e < Dn; e += 256) {
            float v = sred[e] + sred[Dn + e] + sred[2 * Dn + e] + sred[3 * Dn + e];
            sbuf[(size_t)gb * Dn + e] = v;
        }
        if (tid == 0) den[gb] = dred[0] + dred[1] + dred[2] + dred[3];
    }
    signal_ctr(ctr + CTR_TOK);

    // ---------------- final GEMM + fused epilogue (blocks 0..63) ----------------
    if (gb < 64) {
        wait_ctr(ctr + CTR_TOK, 512);
        wait_ctr(ctr + CTR_WOV, 64);
        wait_ctr(ctr + CTR_WOZ, 8);
        int rt = gb >> 3, ct = gb & 7;
        int m0 = rt * 64, n0 = ct * 64;
        if (tid < 64) {
            float dv = den[m0 + tid];
            ssv[tid] = (dv > 0.f) ? 1.f / dv : 0.f;
        }
        __syncthreads();
        gemm_tile<64, true, 1, true, true>(sbuf, 0, m0, wov, n0, 0, 32, ssv,
                                           out, As, Bs, tid,
                                           den, nvalid, z, woz, bo);
    }
}

extern "C" void kernel_launch(void* const* d_in, const int* in_sizes, int n_in,
                              void* d_out, int out_size, void* d_ws, size_t ws_size,
                              hipStream_t stream) {
    const float* feats = (const float*)d_in[0];
    // d_in[1] = coords: unused by the reference
    const unsigned char* maskb = (const unsigned char*)d_in[2];
    const float* z  = (const float*)d_in[3];
    const float* Wq = (const float*)d_in[4];
    const float* Wk = (const float*)d_in[5];
    const float* Wv = (const float*)d_in[6];
    const float* Wo = (const float*)d_in[7];
    const float* bo = (const float*)d_in[8];
    float* out = (float*)d_out;

    // layout kept byte-identical to the validated rounds; wp region now holds
    // only the flag counters (wov/op partial buffers eliminated).
    int*   nvalid = (int*)d_ws + 16;
    int*   idx    = nvalid + 64;
    float* fbase  = (float*)(idx + Bn * Nn);
    float* qp     = fbase;                 // 4 x 32768
    float* woz    = qp   + 4 * 32768;      // 32768 used (region 4x)
    float* qkp    = woz  + 4 * 32768;      // 8 x 32768
    float* wov    = qkp  + 8 * 32768;      // 262144
    float* sbuf   = wov  + 262144;         // 262144
    float* den    = sbuf + 262144;         // 1024 (padded)
    float* wp     = den  + 1024;           // counters live here now
    unsigned int* ctr = (unsigned int*)wp;

    hipMemsetAsync(ctr, 0, 1024, stream);  // zero flag counters

    k_fused<<<NBLK, 256, 0, stream>>>(
        feats, maskb, z, Wq, Wk, Wv, Wo, bo, out,
        ctr, nvalid, idx, qp, woz, qkp, wov, sbuf, den);
}

// Round 5
// 194.337 us; speedup vs baseline: 2.9987x; 1.1141x over previous
//
#include <hip/hip_runtime.h>
#include <math.h>

#define Bn 8
#define Nn 4096
#define Dn 512
#define Ln 64
#define NBLK 512

// ---------------------------------------------------------------------------
// Shared-memory-tiled fp32 GEMM building block, BK-wide k-steps.
//   C_tile(64 x 64) += A[m0.., kbase..kbase+BK*ksteps) @ Beff
//   BT=false: Beff[k][n] = B[k*512 + n];  BT=true: Beff[k][n] = B[n*512 + k]
//   NPART>1: A is NPART partials (stride apstride) summed during staging.
//   SCALE: multiply A row r by sv[r] during staging.
//   EPI: fused epilogue — per output row:
//     nvalid[b]==0 -> z[l]; den[row]>0 -> acc+bo; else -> woz[l]+bo.
// Round-4 post-mortem: BK=16 made every GEMM a chain of serial λ (stage ->
// barrier -> compute -> barrier); 48 dependent steps x ~2us explained the
// 130us. BK=128 stages 8 independent float4/thread in ONE λ: q 8->1 steps,
// qk 4->1, final 32->4. As/Bs are flat [BK][68] (pad 68 keeps the validated
// 2-way-max bank pattern). kk ascends 0..K-1 exactly as before => identical
// FP summation order.
// 256 threads, micro-tile 4x4.
// ---------------------------------------------------------------------------
template<int BK, bool BT, int NPART, bool SCALE, bool EPI = false>
__device__ __forceinline__ void gemm_tile(
    const float* A, size_t apstride, int m0,
    const float* B, int n0, int kbase, int ksteps,
    const float* sv,
    float* dst,
    float* As, float* Bs, int tid,
    const float* eden = nullptr, const int* env = nullptr,
    const float* ez = nullptr, const float* ewoz = nullptr,
    const float* ebo = nullptr)
{
    constexpr int NC = BK / 16;
    const int ty = tid >> 4;
    const int tx = tid & 15;
    float acc[4][4];
    #pragma unroll
    for (int m = 0; m < 4; m++)
        #pragma unroll
        for (int n = 0; n < 4; n++) acc[m][n] = 0.f;

    for (int s = 0; s < ksteps; s++) {
        const int k0 = kbase + s * BK;
        // ---- stage A (64 rows x BK k), transposed into As[kk][row] ----
        {
            int r = tid >> 2, kq = tid & 3;
            #pragma unroll
            for (int c = 0; c < NC; c++) {
                int kk = c * 16 + kq * 4;
                float4 v = *(const float4*)&A[(size_t)(m0 + r) * Dn + k0 + kk];
                #pragma unroll
                for (int p = 1; p < NPART; p++) {
                    float4 w = *(const float4*)&A[(size_t)p * apstride +
                                                  (size_t)(m0 + r) * Dn + k0 + kk];
                    v.x += w.x; v.y += w.y; v.z += w.z; v.w += w.w;
                }
                if (SCALE) { float sc = sv[r]; v.x *= sc; v.y *= sc; v.z *= sc; v.w *= sc; }
                As[(kk + 0) * 68 + r] = v.x;
                As[(kk + 1) * 68 + r] = v.y;
                As[(kk + 2) * 68 + r] = v.z;
                As[(kk + 3) * 68 + r] = v.w;
            }
        }
        // ---- stage B (BK k x 64 cols) ----
        if (!BT) {
            int kk0 = tid >> 4, jq = tid & 15;
            #pragma unroll
            for (int c = 0; c < NC; c++) {
                int kk = c * 16 + kk0;
                *(float4*)&Bs[kk * 68 + jq * 4] =
                    *(const float4*)&B[(size_t)(k0 + kk) * Dn + n0 + jq * 4];
            }
        } else {
            int j = tid >> 2, kq = tid & 3;
            #pragma unroll
            for (int c = 0; c < NC; c++) {
                int kb = c * 16 + kq * 4;
                float4 v = *(const float4*)&B[(size_t)(n0 + j) * Dn + k0 + kb];
                Bs[(kb + 0) * 68 + j] = v.x;
                Bs[(kb + 1) * 68 + j] = v.y;
                Bs[(kb + 2) * 68 + j] = v.z;
                Bs[(kb + 3) * 68 + j] = v.w;
            }
        }
        __syncthreads();
        // ---- inner product ----
        #pragma unroll 16
        for (int kk = 0; kk < BK; kk++) {
            float4 a = *(const float4*)&As[kk * 68 + ty * 4];
            float4 b = *(const float4*)&Bs[kk * 68 + tx * 4];
            float av[4] = {a.x, a.y, a.z, a.w};
            float bv[4] = {b.x, b.y, b.z, b.w};
            #pragma unroll
            for (int m = 0; m < 4; m++)
                #pragma unroll
                for (int n = 0; n < 4; n++) acc[m][n] += av[m] * bv[n];
        }
        __syncthreads();
    }
    // ---- write tile ----
    if constexpr (EPI) {
        int col = n0 + tx * 4;
        float4 bv = *(const float4*)&ebo[col];
        #pragma unroll
        for (int m = 0; m < 4; m++) {
            int row = m0 + ty * 4 + m;
            int bb = row >> 6, ll = row & 63;
            float4 v;
            if (env[bb] == 0) {
                v = *(const float4*)&ez[(size_t)ll * Dn + col];
            } else if (eden[row] > 0.f) {
                v.x = acc[m][0] + bv.x; v.y = acc[m][1] + bv.y;
                v.z = acc[m][2] + bv.z; v.w = acc[m][3] + bv.w;
            } else {
                float4 wz = *(const float4*)&ewoz[(size_t)ll * Dn + col];
                v.x = wz.x + bv.x; v.y = wz.y + bv.y;
                v.z = wz.z + bv.z; v.w = wz.w + bv.w;
            }
            *(float4*)&dst[(size_t)row * Dn + col] = v;
        }
    } else {
        #pragma unroll
        for (int m = 0; m < 4; m++) {
            size_t base = (size_t)(m0 + ty * 4 + m) * Dn + n0;
            float4 o = {acc[m][0], acc[m][1], acc[m][2], acc[m][3]};
            *(float4*)&dst[base + tx * 4] = o;
        }
    }
}

// ---------------------------------------------------------------------------
// Producer->consumer flags (validated round 4): SYSTEM-scope relaxed atomics
// execute at the coherent point (MALL) — no staleness, no per-poll cache ops.
// One agent fence per signal (release) / per wait-exit (acquire).
// TOK is split into 8 sub-counters on separate 128B lines (gb&7) to cut
// same-line RMW serialization of 512 arrivals -> 64 per line.
// ---------------------------------------------------------------------------
#define CTR_CMP   0     // -> 8
#define CTR_Q     32    // -> 32
#define CTR_QK    64    // -> 64
#define CTR_WOV   96    // -> 64
#define CTR_WOZ   128   // -> 8
#define CTR_TOK   160   // 8 lines at +32*g, each -> 64

template<int SLP>
__device__ __forceinline__ void wait_ctr(unsigned int* p, unsigned int tgt) {
    if (threadIdx.x == 0) {
        while (__hip_atomic_load(p, __ATOMIC_RELAXED, __HIP_MEMORY_SCOPE_SYSTEM) < tgt)
            __builtin_amdgcn_s_sleep(SLP);
        __threadfence();   // acquire: invalidate local caches once
    }
    __syncthreads();
}

__device__ __forceinline__ void wait_tok(unsigned int* base) {
    if (threadIdx.x == 0) {
        for (;;) {
            unsigned int mn = 0xffffffffu;
            #pragma unroll
            for (int g = 0; g < 8; g++) {
                unsigned int v = __hip_atomic_load(base + g * 32, __ATOMIC_RELAXED,
                                                   __HIP_MEMORY_SCOPE_SYSTEM);
                mn = v < mn ? v : mn;
            }
            if (mn >= 64u) break;
            __builtin_amdgcn_s_sleep(8);
        }
        __threadfence();
    }
    __syncthreads();
}

__device__ __forceinline__ void signal_ctr(unsigned int* p) {
    __syncthreads();       // all block stores issued & drained
    if (threadIdx.x == 0) {
        __threadfence();   // release: write back L2 once
        __hip_atomic_fetch_add(p, 1u, __ATOMIC_RELAXED, __HIP_MEMORY_SCOPE_SYSTEM);
    }
}

// ============================================================================
// Single fused kernel, flag-DAG schedule. 512 x 256.
//   roles: 64..95  q   = z@Wq^T   (Ksplit4, BK=128: ONE k-step)
//          96..159 qk  = q@Wk     (Ksplit8, BK=64: ONE k-step, waits q)
//          160..223 wov = Wo@Wv   (direct K=512, BK=128: 4 steps)
//          224..231 woz = z@Wo^T  (direct, 4 steps)
//          232..239 mask compaction
//   all:   token pass (waits cmp, qk)
//   0..63: out tile = (s/den)@wov^T + fused epilogue (waits tok/wov/woz)
// LDS: As|Bs = 2 x 128x68 floats (68.0 KB) + ~1.3 KB misc; sred aliases As.
// 2 blocks/CU -> all 512 co-resident.
// ============================================================================
__global__ void __launch_bounds__(256) k_fused(
    const float* __restrict__ feats, const unsigned char* __restrict__ maskbytes,
    const float* __restrict__ z, const float* __restrict__ Wq,
    const float* __restrict__ Wk, const float* __restrict__ Wv,
    const float* __restrict__ Wo, const float* __restrict__ bo,
    float* __restrict__ out,
    unsigned int* ctr,
    int* nvalid, int* idx, float* qp, float* woz, float* qkp,
    float* wov, float* sbuf, float* den)
{
    __shared__ float smem[2 * 128 * 68];
    __shared__ int scanbuf[256];
    __shared__ int cflags[4];
    __shared__ float dred[4];
    __shared__ float ssv[64];

    float* As   = smem;              // [128][68]
    float* Bs   = smem + 128 * 68;   // [128][68]
    float* sred = smem;              // token-phase alias over As (8 KB < 34.8 KB)

    int tid = threadIdx.x;
    int gb = blockIdx.x;

    // --------------------------- producer roles ---------------------------
    if (gb >= 64 && gb < 96) {            // q = z @ Wq^T, Ksplit4, 1 step
        int t = gb - 64; int ks = t & 3; int nt = t >> 2;
        gemm_tile<128, true, 1, false>(z, 0, 0, Wq, nt * 64,
                                       ks * 128, 1, nullptr,
                                       qp + (size_t)ks * 32768, As, Bs, tid);
        signal_ctr(ctr + CTR_Q);
    } else if (gb >= 96 && gb < 160) {    // qk = (sum qp) @ Wk, Ksplit8, 1 step
        wait_ctr<8>(ctr + CTR_Q, 32);
        int t = gb - 96; int ks = t & 7; int nt = t >> 3;
        gemm_tile<64, false, 4, false>(qp, 32768, 0, Wk, nt * 64,
                                       ks * 64, 1, nullptr,
                                       qkp + (size_t)ks * 32768, As, Bs, tid);
        signal_ctr(ctr + CTR_QK);
    } else if (gb >= 160 && gb < 224) {   // wov = Wo @ Wv, direct K=512
        int t = gb - 160; int rt = t >> 3; int ct = t & 7;
        gemm_tile<128, false, 1, false>(Wo, 0, rt * 64, Wv, ct * 64,
                                        0, 4, nullptr, wov, As, Bs, tid);
        signal_ctr(ctr + CTR_WOV);
    } else if (gb >= 224 && gb < 232) {   // woz = z @ Wo^T, direct K=512
        int nt = gb - 224;
        gemm_tile<128, true, 1, false>(z, 0, 0, Wo, nt * 64,
                                       0, 4, nullptr, woz, As, Bs, tid);
        signal_ctr(ctr + CTR_WOZ);
    } else if (gb >= 232 && gb < 240) {   // mask compaction, one block/sample
        int b = gb - 232;
        if (tid == 0) { cflags[0] = 0; cflags[1] = 0; cflags[2] = 0; }
        __syncthreads();
        int lge2 = 0, lb1 = 0, lm = 0;
        for (int p = tid; p < 4096; p += 256) {
            unsigned int v = maskbytes[p];
            if (v > 1u) lge2 = 1;
            if (v != 0u) {
                if ((p & 3) == 1) lb1 = 1;
                if ((p & 3) != 0) lm = 1;
            }
        }
        if (lge2) atomicOr(&cflags[0], 1);
        if (lb1)  atomicOr(&cflags[1], 1);
        if (lm)   atomicOr(&cflags[2], 1);
        __syncthreads();
        if (tid == 0) cflags[3] = cflags[0] ? (cflags[1] ? 2 : 4) : (cflags[2] ? 1 : 4);
        __syncthreads();
        int w = cflags[3];

        int base = tid * 16;
        int cnt = 0;
        int validbits[16];
        for (int e = 0; e < 16; e++) {
            int i = base + e;
            size_t byteoff = ((size_t)b * Nn + i) * (size_t)w;
            unsigned int nz = 0;
            for (int q = 0; q < w; q++) nz |= maskbytes[byteoff + q];
            int valid = (nz == 0) ? 1 : 0;
            validbits[e] = valid;
            cnt += valid;
        }
        scanbuf[tid] = cnt;
        __syncthreads();
        for (int off = 1; off < 256; off <<= 1) {
            int v = (tid >= off) ? scanbuf[tid - off] : 0;
            __syncthreads();
            scanbuf[tid] += v;
            __syncthreads();
        }
        int pos = scanbuf[tid] - cnt;
        for (int e = 0; e < 16; e++) {
            if (validbits[e]) { idx[b * Nn + pos] = base + e; pos++; }
        }
        if (tid == 255) nvalid[b] = scanbuf[255];
        signal_ctr(ctr + CTR_CMP);
    }

    // --------------------------- token pass (all blocks) ---------------------------
    wait_ctr<16>(ctr + CTR_CMP, 8);
    wait_ctr<16>(ctr + CTR_QK, 64);
    {
        int wv = tid >> 6;
        int lane = tid & 63;
        int b = gb / Ln;
        int l = gb % Ln;
        int nv = nvalid[b];
        int seg_size = nv / Ln; if (seg_size < 1) seg_size = 1;
        int used = Ln * seg_size; if (used > nv) used = nv;
        int r0 = l * seg_size;
        int r1 = r0 + seg_size; if (r1 > used) r1 = used;

        float4 qa = {0.f,0.f,0.f,0.f}, qb = {0.f,0.f,0.f,0.f};
        #pragma unroll
        for (int p = 0; p < 8; p++) {
            const float4* q4 = (const float4*)(qkp + (size_t)p * 32768 +
                                               (size_t)l * Dn + lane * 8);
            float4 a = q4[0], c = q4[1];
            qa.x += a.x; qa.y += a.y; qa.z += a.z; qa.w += a.w;
            qb.x += c.x; qb.y += c.y; qb.z += c.z; qb.w += c.w;
        }
        float qf[8] = {qa.x, qa.y, qa.z, qa.w, qb.x, qb.y, qb.z, qb.w};

        float sacc[8] = {0,0,0,0,0,0,0,0};
        float dacc = 0.f;
        const float inv_d = 1.0f / (float)Dn;
        const float inv_temp = 1.0f / 22.62741699796952f;  // 1/sqrt(512)

        for (int r = r0 + wv * 2; r < r1; r += 8) {
            int has2 = (r + 1 < r1);
            int t0 = idx[b * Nn + r];
            int t1 = has2 ? idx[b * Nn + r + 1] : t0;
            const float4* p0 = (const float4*)(feats + ((size_t)b * Nn + t0) * Dn + lane * 8);
            const float4* p1 = (const float4*)(feats + ((size_t)b * Nn + t1) * Dn + lane * 8);
            float4 xa0 = p0[0], xb0 = p0[1];
            float4 xa1 = p1[0], xb1 = p1[1];
            float x0[8] = {xa0.x, xa0.y, xa0.z, xa0.w, xb0.x, xb0.y, xb0.z, xb0.w};
            float x1[8] = {xa1.x, xa1.y, xa1.z, xa1.w, xb1.x, xb1.y, xb1.z, xb1.w};
            float sum0 = 0.f, ssq0 = 0.f, sum1 = 0.f, ssq1 = 0.f;
            #pragma unroll
            for (int j = 0; j < 8; j++) {
                sum0 += x0[j]; ssq0 += x0[j] * x0[j];
                sum1 += x1[j]; ssq1 += x1[j] * x1[j];
            }
            #pragma unroll
            for (int off = 32; off > 0; off >>= 1) {
                sum0 += __shfl_xor(sum0, off);
                ssq0 += __shfl_xor(ssq0, off);
                sum1 += __shfl_xor(sum1, off);
                ssq1 += __shfl_xor(ssq1, off);
            }
            float mu0 = sum0 * inv_d, mu1 = sum1 * inv_d;
            float rstd0 = rsqrtf(ssq0 * inv_d - mu0 * mu0 + 1e-5f);
            float rstd1 = rsqrtf(ssq1 * inv_d - mu1 * mu1 + 1e-5f);
            float ln0[8], ln1[8];
            float dot0 = 0.f, dot1 = 0.f;
            #pragma unroll
            for (int j = 0; j < 8; j++) {
                ln0[j] = (x0[j] - mu0) * rstd0; dot0 += ln0[j] * qf[j];
                ln1[j] = (x1[j] - mu1) * rstd1; dot1 += ln1[j] * qf[j];
            }
            #pragma unroll
            for (int off = 32; off > 0; off >>= 1) {
                dot0 += __shfl_xor(dot0, off);
                dot1 += __shfl_xor(dot1, off);
            }
            float lg0 = fminf(5.0f, fmaxf(-5.0f, dot0 * inv_temp));
            float lg1 = fminf(5.0f, fmaxf(-5.0f, dot1 * inv_temp));
            float e0 = expf(lg0);
            float e1 = has2 ? expf(lg1) : 0.f;
            #pragma unroll
            for (int j = 0; j < 8; j++) sacc[j] += e0 * ln0[j] + e1 * ln1[j];
            dacc += e0 + e1;
        }

        #pragma unroll
        for (int j = 0; j < 8; j++) sred[wv * Dn + lane * 8 + j] = sacc[j];
        if (lane == 0) dred[wv] = dacc;
        __syncthreads();
        for (int e = tid; e < Dn; e += 256) {
            float v = sred[e] + sred[Dn + e] + sred[2 * Dn + e] + sred[3 * Dn + e];
            sbuf[(size_t)gb * Dn + e] = v;
        }
        if (tid == 0) den[gb] = dred[0] + dred[1] + dred[2] + dred[3];
    }
    signal_ctr(ctr + CTR_TOK + (gb & 7) * 32);

    // ---------------- final GEMM + fused epilogue (blocks 0..63) ----------------
    if (gb < 64) {
        wait_tok(ctr + CTR_TOK);
        wait_ctr<8>(ctr + CTR_WOV, 64);
        wait_ctr<8>(ctr + CTR_WOZ, 8);
        int rt = gb >> 3, ct = gb & 7;
        int m0 = rt * 64, n0 = ct * 64;
        if (tid < 64) {
            float dv = den[m0 + tid];
            ssv[tid] = (dv > 0.f) ? 1.f / dv : 0.f;
        }
        __syncthreads();
        gemm_tile<128, true, 1, true, true>(sbuf, 0, m0, wov, n0, 0, 4, ssv,
                                            out, As, Bs, tid,
                                            den, nvalid, z, woz, bo);
    }
}

extern "C" void kernel_launch(void* const* d_in, const int* in_sizes, int n_in,
                              void* d_out, int out_size, void* d_ws, size_t ws_size,
                              hipStream_t stream) {
    const float* feats = (const float*)d_in[0];
    // d_in[1] = coords: unused by the reference
    const unsigned char* maskb = (const unsigned char*)d_in[2];
    const float* z  = (const float*)d_in[3];
    const float* Wq = (const float*)d_in[4];
    const float* Wk = (const float*)d_in[5];
    const float* Wv = (const float*)d_in[6];
    const float* Wo = (const float*)d_in[7];
    const float* bo = (const float*)d_in[8];
    float* out = (float*)d_out;

    int*   nvalid = (int*)d_ws + 16;
    int*   idx    = nvalid + 64;
    float* fbase  = (float*)(idx + Bn * Nn);
    float* qp     = fbase;                 // 4 x 32768
    float* woz    = qp   + 4 * 32768;      // 32768 used (region 4x)
    float* qkp    = woz  + 4 * 32768;      // 8 x 32768
    float* wov    = qkp  + 8 * 32768;      // 262144
    float* sbuf   = wov  + 262144;         // 262144
    float* den    = sbuf + 262144;         // 1024 (padded)
    float* wp     = den  + 1024;           // counters live here
    unsigned int* ctr = (unsigned int*)wp;

    hipMemsetAsync(ctr, 0, 2048, stream);  // zero flag counters (incl. TOK x8)

    k_fused<<<NBLK, 256, 0, stream>>>(
        feats, maskb, z, Wq, Wk, Wv, Wo, bo, out,
        ctr, nvalid, idx, qp, woz, qkp, wov, sbuf, den);
}

// Round 6
// 165.916 us; speedup vs baseline: 3.5124x; 1.1713x over previous
//
#include <hip/hip_runtime.h>
#include <math.h>

#define Bn 8
#define Nn 4096
#define Dn 512
#define Ln 64
#define NBLK 512

typedef float v4f __attribute__((ext_vector_type(4)));

// ---------------------------------------------------------------------------
// System-scope (MALL-coherent) load/store helpers. Round-5 post-mortem: the
// ~1700 __threadfence ops (each = buffer_wbl2 + buffer_inv on gfx950, since
// per-XCD L2s aren't cross-coherent) cost ~80us AND cold-cached every phase.
// sc0 sc1 stores write through to the MALL (nothing dirty in L2 -> no release
// fence needed beyond vmcnt drain); sc0 sc1 loads read the MALL (no acquire
// invalidate needed). Inputs stay hot in L2.
// ---------------------------------------------------------------------------
__device__ __forceinline__ void ld_sys_f4x8(v4f& r0, v4f& r1, v4f& r2, v4f& r3,
                                            v4f& r4, v4f& r5, v4f& r6, v4f& r7,
                                            const float* base) {
    asm volatile(
        "global_load_dwordx4 %0, %8, off sc0 sc1\n\t"
        "global_load_dwordx4 %1, %8, off offset:64 sc0 sc1\n\t"
        "global_load_dwordx4 %2, %8, off offset:128 sc0 sc1\n\t"
        "global_load_dwordx4 %3, %8, off offset:192 sc0 sc1\n\t"
        "global_load_dwordx4 %4, %8, off offset:256 sc0 sc1\n\t"
        "global_load_dwordx4 %5, %8, off offset:320 sc0 sc1\n\t"
        "global_load_dwordx4 %6, %8, off offset:384 sc0 sc1\n\t"
        "global_load_dwordx4 %7, %8, off offset:448 sc0 sc1\n\t"
        "s_waitcnt vmcnt(0)"
        : "=&v"(r0), "=&v"(r1), "=&v"(r2), "=&v"(r3),
          "=&v"(r4), "=&v"(r5), "=&v"(r6), "=&v"(r7)
        : "v"(base) : "memory");
}
__device__ __forceinline__ void ld_sys_f4x2(v4f& a, v4f& b, const float* base) {
    asm volatile(
        "global_load_dwordx4 %0, %2, off sc0 sc1\n\t"
        "global_load_dwordx4 %1, %2, off offset:16 sc0 sc1\n\t"
        "s_waitcnt vmcnt(0)"
        : "=&v"(a), "=&v"(b) : "v"(base) : "memory");
}
__device__ __forceinline__ v4f ld_sys_f4(const float* p) {
    v4f r;
    asm volatile("global_load_dwordx4 %0, %1, off sc0 sc1\n\ts_waitcnt vmcnt(0)"
                 : "=&v"(r) : "v"(p) : "memory");
    return r;
}
__device__ __forceinline__ float ld_sys_f32(const float* p) {
    float r;
    asm volatile("global_load_dword %0, %1, off sc0 sc1\n\ts_waitcnt vmcnt(0)"
                 : "=&v"(r) : "v"(p) : "memory");
    return r;
}
__device__ __forceinline__ int ld_sys_i32(const int* p) {
    int r;
    asm volatile("global_load_dword %0, %1, off sc0 sc1\n\ts_waitcnt vmcnt(0)"
                 : "=&v"(r) : "v"(p) : "memory");
    return r;
}
__device__ __forceinline__ void st_sys_f4(float* p, v4f v) {
    asm volatile("global_store_dwordx4 %0, %1, off sc0 sc1" :: "v"(p), "v"(v) : "memory");
}
__device__ __forceinline__ void st_sys_f32(float* p, float v) {
    asm volatile("global_store_dword %0, %1, off sc0 sc1" :: "v"(p), "v"(v) : "memory");
}
__device__ __forceinline__ void st_sys_i32(int* p, int v) {
    asm volatile("global_store_dword %0, %1, off sc0 sc1" :: "v"(p), "v"(v) : "memory");
}

// ---------------------------------------------------------------------------
// Fence-free flags (round-4-validated system-scope relaxed atomics at MALL).
// signal: __syncthreads drains the block's (write-through) stores to the MALL,
// then one relaxed system atomicAdd. wait: relaxed system poll; no acquire
// fence needed because consumers read flagged data with sc0 sc1 bypass loads.
// ---------------------------------------------------------------------------
#define CTR_CMP   0     // -> 8
#define CTR_Q     32    // -> 8
#define CTR_QK    64    // -> 32
#define CTR_WOV   96    // -> 64
#define CTR_WOZ   128   // -> 8
#define CTR_TOK   160   // 8 lines at +32*g, each -> 64

template<int SLP>
__device__ __forceinline__ void wait_ctr(unsigned int* p, unsigned int tgt) {
    if (threadIdx.x == 0) {
        while (__hip_atomic_load(p, __ATOMIC_RELAXED, __HIP_MEMORY_SCOPE_SYSTEM) < tgt)
            __builtin_amdgcn_s_sleep(SLP);
    }
    __syncthreads();
}
__device__ __forceinline__ void wait_tok(unsigned int* base) {
    if (threadIdx.x == 0) {
        for (;;) {
            unsigned int mn = 0xffffffffu;
            #pragma unroll
            for (int g = 0; g < 8; g++) {
                unsigned int v = __hip_atomic_load(base + g * 32, __ATOMIC_RELAXED,
                                                   __HIP_MEMORY_SCOPE_SYSTEM);
                mn = v < mn ? v : mn;
            }
            if (mn >= 64u) break;
            __builtin_amdgcn_s_sleep(8);
        }
    }
    __syncthreads();
}
__device__ __forceinline__ void signal_ctr(unsigned int* p) {
    __syncthreads();       // drains vmcnt -> all sc1 stores at the MALL
    if (threadIdx.x == 0) {
        __hip_atomic_fetch_add(p, 1u, __ATOMIC_RELAXED, __HIP_MEMORY_SCOPE_SYSTEM);
    }
}

// ---------------------------------------------------------------------------
// Tiled fp32 GEMM, BK=128 (validated round 5), with per-operand bypass flags.
//   C_tile(64x64) += A[m0..] @ Beff ; BT as before.
//   BYPA/BYPB: stage operand via sc0 sc1 bypass loads (cross-block data).
//   SCALE: multiply A row r by sv[r] (LDS) during staging.
//   WTST: write-through (sc0 sc1) output stores (cross-block data).
//   EPI: fused epilogue (final GEMM): per row ll = row&63,
//     nv_epi==0 -> z[ll]; sv[ll]>0 -> acc+bo; else -> woz[ll]+bo.
// ---------------------------------------------------------------------------
template<bool BT, bool BYPA, bool BYPB, bool SCALE, bool WTST, bool EPI>
__device__ __forceinline__ void gemm_tile(
    const float* A, int m0,
    const float* B, int n0, int kbase, int ksteps,
    const float* sv, float* dst,
    float* As, float* Bs, int tid,
    int nv_epi = 0, const float* ez = nullptr,
    const float* ewoz = nullptr, const float* ebo = nullptr)
{
    const int ty = tid >> 4;
    const int tx = tid & 15;
    float acc[4][4];
    #pragma unroll
    for (int m = 0; m < 4; m++)
        #pragma unroll
        for (int n = 0; n < 4; n++) acc[m][n] = 0.f;

    for (int s = 0; s < ksteps; s++) {
        const int k0 = kbase + s * 128;
        // ---- stage A (64 rows x 128 k) -> As[kk][row] ----
        {
            int r = tid >> 2, kq = tid & 3;
            const float* ab = &A[(size_t)(m0 + r) * Dn + k0 + kq * 4];
            v4f v[8];
            if constexpr (BYPA) {
                ld_sys_f4x8(v[0], v[1], v[2], v[3], v[4], v[5], v[6], v[7], ab);
            } else {
                #pragma unroll
                for (int c = 0; c < 8; c++) v[c] = *(const v4f*)(ab + c * 16);
            }
            if constexpr (SCALE) {
                float sc = sv[r];
                #pragma unroll
                for (int c = 0; c < 8; c++) v[c] *= sc;
            }
            #pragma unroll
            for (int c = 0; c < 8; c++) {
                int kk = c * 16 + kq * 4;
                As[(kk + 0) * 68 + r] = v[c].x;
                As[(kk + 1) * 68 + r] = v[c].y;
                As[(kk + 2) * 68 + r] = v[c].z;
                As[(kk + 3) * 68 + r] = v[c].w;
            }
        }
        // ---- stage B (128 k x 64 cols) ----
        if constexpr (!BT) {
            int kk0 = tid >> 4, jq = tid & 15;
            #pragma unroll
            for (int c = 0; c < 8; c++) {
                int kk = c * 16 + kk0;
                *(v4f*)&Bs[kk * 68 + jq * 4] =
                    *(const v4f*)&B[(size_t)(k0 + kk) * Dn + n0 + jq * 4];
            }
        } else {
            int j = tid >> 2, kq = tid & 3;
            const float* bb = &B[(size_t)(n0 + j) * Dn + k0 + kq * 4];
            v4f v[8];
            if constexpr (BYPB) {
                ld_sys_f4x8(v[0], v[1], v[2], v[3], v[4], v[5], v[6], v[7], bb);
            } else {
                #pragma unroll
                for (int c = 0; c < 8; c++) v[c] = *(const v4f*)(bb + c * 16);
            }
            #pragma unroll
            for (int c = 0; c < 8; c++) {
                int kb = c * 16 + kq * 4;
                Bs[(kb + 0) * 68 + j] = v[c].x;
                Bs[(kb + 1) * 68 + j] = v[c].y;
                Bs[(kb + 2) * 68 + j] = v[c].z;
                Bs[(kb + 3) * 68 + j] = v[c].w;
            }
        }
        __syncthreads();
        // ---- inner product ----
        #pragma unroll 16
        for (int kk = 0; kk < 128; kk++) {
            v4f a = *(const v4f*)&As[kk * 68 + ty * 4];
            v4f b = *(const v4f*)&Bs[kk * 68 + tx * 4];
            float av[4] = {a.x, a.y, a.z, a.w};
            float bv[4] = {b.x, b.y, b.z, b.w};
            #pragma unroll
            for (int m = 0; m < 4; m++)
                #pragma unroll
                for (int n = 0; n < 4; n++) acc[m][n] += av[m] * bv[n];
        }
        __syncthreads();
    }
    // ---- write tile ----
    if constexpr (EPI) {
        int col = n0 + tx * 4;
        v4f bv = *(const v4f*)&ebo[col];
        #pragma unroll
        for (int m = 0; m < 4; m++) {
            int row = m0 + ty * 4 + m;
            int ll = row & 63;
            v4f v;
            if (nv_epi == 0) {
                v = *(const v4f*)&ez[(size_t)ll * Dn + col];
            } else if (sv[ll] > 0.f) {
                v.x = acc[m][0] + bv.x; v.y = acc[m][1] + bv.y;
                v.z = acc[m][2] + bv.z; v.w = acc[m][3] + bv.w;
            } else {
                v4f wz = ld_sys_f4(&ewoz[(size_t)ll * Dn + col]);
                v = wz + bv;
            }
            *(v4f*)&dst[(size_t)row * Dn + col] = v;
        }
    } else {
        #pragma unroll
        for (int m = 0; m < 4; m++) {
            size_t base = (size_t)(m0 + ty * 4 + m) * Dn + n0;
            v4f o = {acc[m][0], acc[m][1], acc[m][2], acc[m][3]};
            if constexpr (WTST) st_sys_f4(&dst[base + tx * 4], o);
            else                *(v4f*)&dst[base + tx * 4] = o;
        }
    }
}

// ============================================================================
// Single fused kernel, fence-free flag DAG. 512 x 256.
//   64..71   q   = z@Wq^T   direct K=512 (4 steps), WT stores
//   96..127  qk  = q@Wk     Ksplit4 (1 step), waits Q; bypass-reads q; WT
//   160..223 wov = Wo@Wv    direct (4 steps), WT
//   224..231 woz = z@Wo^T   direct (4 steps), WT
//   232..239 mask compaction, sc1 scatter stores
//   all:     token pass (waits CMP, QK; bypass-reads qk/idx/nvalid;
//            sc1 stores sbuf/den)
//   0..63:   final tile = (s/den)@wov^T + fused epilogue
//            (waits TOK/WOV/WOZ; bypass-reads sbuf/wov/den/woz/nvalid)
// LDS ~71 KB -> 2 blocks/CU, all 512 co-resident.
// ============================================================================
__global__ void __launch_bounds__(256) k_fused(
    const float* __restrict__ feats, const unsigned char* __restrict__ maskbytes,
    const float* __restrict__ z, const float* __restrict__ Wq,
    const float* __restrict__ Wk, const float* __restrict__ Wv,
    const float* __restrict__ Wo, const float* __restrict__ bo,
    float* __restrict__ out,
    unsigned int* ctr,
    int* nvalid, int* idx, float* qbuf, float* woz, float* qkp,
    float* wov, float* sbuf, float* den)
{
    __shared__ float smem[2 * 128 * 68];
    __shared__ int scanbuf[256];
    __shared__ int cflags[4];
    __shared__ float dred[4];
    __shared__ float ssv[64];
    __shared__ int sidx[64];
    __shared__ int snv;

    float* As   = smem;              // [128][68]
    float* Bs   = smem + 128 * 68;   // [128][68]
    float* sred = smem;              // token-phase alias over As

    int tid = threadIdx.x;
    int gb = blockIdx.x;

    // --------------------------- producer roles ---------------------------
    if (gb >= 64 && gb < 72) {            // q = z @ Wq^T, direct K=512
        int nt = gb - 64;
        gemm_tile<true, false, false, false, true, false>(
            z, 0, Wq, nt * 64, 0, 4, nullptr, qbuf, As, Bs, tid);
        signal_ctr(ctr + CTR_Q);
    } else if (gb >= 96 && gb < 128) {    // qk = q @ Wk, Ksplit4
        wait_ctr<8>(ctr + CTR_Q, 8);
        int t = gb - 96; int ks = t & 3; int nt = t >> 2;
        gemm_tile<false, true, false, false, true, false>(
            qbuf, 0, Wk, nt * 64, ks * 128, 1, nullptr,
            qkp + (size_t)ks * 32768, As, Bs, tid);
        signal_ctr(ctr + CTR_QK);
    } else if (gb >= 160 && gb < 224) {   // wov = Wo @ Wv, direct K=512
        int t = gb - 160; int rt = t >> 3; int ct = t & 7;
        gemm_tile<false, false, false, false, true, false>(
            Wo, rt * 64, Wv, ct * 64, 0, 4, nullptr, wov, As, Bs, tid);
        signal_ctr(ctr + CTR_WOV);
    } else if (gb >= 224 && gb < 232) {   // woz = z @ Wo^T, direct K=512
        int nt = gb - 224;
        gemm_tile<true, false, false, false, true, false>(
            z, 0, Wo, nt * 64, 0, 4, nullptr, woz, As, Bs, tid);
        signal_ctr(ctr + CTR_WOZ);
    } else if (gb >= 232 && gb < 240) {   // mask compaction, one block/sample
        int b = gb - 232;
        if (tid == 0) { cflags[0] = 0; cflags[1] = 0; cflags[2] = 0; }
        __syncthreads();
        int lge2 = 0, lb1 = 0, lm = 0;
        for (int p = tid; p < 4096; p += 256) {
            unsigned int v = maskbytes[p];
            if (v > 1u) lge2 = 1;
            if (v != 0u) {
                if ((p & 3) == 1) lb1 = 1;
                if ((p & 3) != 0) lm = 1;
            }
        }
        if (lge2) atomicOr(&cflags[0], 1);
        if (lb1)  atomicOr(&cflags[1], 1);
        if (lm)   atomicOr(&cflags[2], 1);
        __syncthreads();
        if (tid == 0) cflags[3] = cflags[0] ? (cflags[1] ? 2 : 4) : (cflags[2] ? 1 : 4);
        __syncthreads();
        int w = cflags[3];

        int base = tid * 16;
        int cnt = 0;
        int validbits[16];
        for (int e = 0; e < 16; e++) {
            int i = base + e;
            size_t byteoff = ((size_t)b * Nn + i) * (size_t)w;
            unsigned int nz = 0;
            for (int q = 0; q < w; q++) nz |= maskbytes[byteoff + q];
            int valid = (nz == 0) ? 1 : 0;
            validbits[e] = valid;
            cnt += valid;
        }
        scanbuf[tid] = cnt;
        __syncthreads();
        for (int off = 1; off < 256; off <<= 1) {
            int v = (tid >= off) ? scanbuf[tid - off] : 0;
            __syncthreads();
            scanbuf[tid] += v;
            __syncthreads();
        }
        int pos = scanbuf[tid] - cnt;
        for (int e = 0; e < 16; e++) {
            if (validbits[e]) { st_sys_i32(&idx[b * Nn + pos], base + e); pos++; }
        }
        if (tid == 255) st_sys_i32(&nvalid[b], scanbuf[255]);
        signal_ctr(ctr + CTR_CMP);
    }

    // --------------------------- token pass (all blocks) ---------------------------
    wait_ctr<16>(ctr + CTR_CMP, 8);
    wait_ctr<16>(ctr + CTR_QK, 32);
    {
        int wv = tid >> 6;
        int lane = tid & 63;
        int b = gb / Ln;
        int l = gb % Ln;
        if (tid == 0) snv = ld_sys_i32(&nvalid[b]);
        __syncthreads();
        int nv = snv;
        int seg_size = nv / Ln; if (seg_size < 1) seg_size = 1;
        int used = Ln * seg_size; if (used > nv) used = nv;
        int r0 = l * seg_size;
        int r1 = r0 + seg_size; if (r1 > used) r1 = used;

        if (tid < 64 && r0 + tid < r1)
            sidx[tid] = ld_sys_i32(&idx[b * Nn + r0 + tid]);

        // qf = row l of qk, summed over 4 K-split partials (bypass reads)
        v4f qa = {0.f, 0.f, 0.f, 0.f}, qb4 = {0.f, 0.f, 0.f, 0.f};
        #pragma unroll
        for (int p = 0; p < 4; p++) {
            v4f a, c;
            ld_sys_f4x2(a, c, qkp + (size_t)p * 32768 + (size_t)l * Dn + lane * 8);
            qa += a; qb4 += c;
        }
        float qf[8] = {qa.x, qa.y, qa.z, qa.w, qb4.x, qb4.y, qb4.z, qb4.w};
        __syncthreads();   // sidx visible

        float sacc[8] = {0,0,0,0,0,0,0,0};
        float dacc = 0.f;
        const float inv_d = 1.0f / (float)Dn;
        const float inv_temp = 1.0f / 22.62741699796952f;  // 1/sqrt(512)

        for (int r = r0 + wv * 2; r < r1; r += 8) {
            int has2 = (r + 1 < r1);
            int t0 = sidx[r - r0];
            int t1 = has2 ? sidx[r + 1 - r0] : t0;
            const float4* p0 = (const float4*)(feats + ((size_t)b * Nn + t0) * Dn + lane * 8);
            const float4* p1 = (const float4*)(feats + ((size_t)b * Nn + t1) * Dn + lane * 8);
            float4 xa0 = p0[0], xb0 = p0[1];
            float4 xa1 = p1[0], xb1 = p1[1];
            float x0[8] = {xa0.x, xa0.y, xa0.z, xa0.w, xb0.x, xb0.y, xb0.z, xb0.w};
            float x1[8] = {xa1.x, xa1.y, xa1.z, xa1.w, xb1.x, xb1.y, xb1.z, xb1.w};
            float sum0 = 0.f, ssq0 = 0.f, sum1 = 0.f, ssq1 = 0.f;
            #pragma unroll
            for (int j = 0; j < 8; j++) {
                sum0 += x0[j]; ssq0 += x0[j] * x0[j];
                sum1 += x1[j]; ssq1 += x1[j] * x1[j];
            }
            #pragma unroll
            for (int off = 32; off > 0; off >>= 1) {
                sum0 += __shfl_xor(sum0, off);
                ssq0 += __shfl_xor(ssq0, off);
                sum1 += __shfl_xor(sum1, off);
                ssq1 += __shfl_xor(ssq1, off);
            }
            float mu0 = sum0 * inv_d, mu1 = sum1 * inv_d;
            float rstd0 = rsqrtf(ssq0 * inv_d - mu0 * mu0 + 1e-5f);
            float rstd1 = rsqrtf(ssq1 * inv_d - mu1 * mu1 + 1e-5f);
            float ln0[8], ln1[8];
            float dot0 = 0.f, dot1 = 0.f;
            #pragma unroll
            for (int j = 0; j < 8; j++) {
                ln0[j] = (x0[j] - mu0) * rstd0; dot0 += ln0[j] * qf[j];
                ln1[j] = (x1[j] - mu1) * rstd1; dot1 += ln1[j] * qf[j];
            }
            #pragma unroll
            for (int off = 32; off > 0; off >>= 1) {
                dot0 += __shfl_xor(dot0, off);
                dot1 += __shfl_xor(dot1, off);
            }
            float lg0 = fminf(5.0f, fmaxf(-5.0f, dot0 * inv_temp));
            float lg1 = fminf(5.0f, fmaxf(-5.0f, dot1 * inv_temp));
            float e0 = expf(lg0);
            float e1 = has2 ? expf(lg1) : 0.f;
            #pragma unroll
            for (int j = 0; j < 8; j++) sacc[j] += e0 * ln0[j] + e1 * ln1[j];
            dacc += e0 + e1;
        }

        #pragma unroll
        for (int j = 0; j < 8; j++) sred[wv * Dn + lane * 8 + j] = sacc[j];
        if (lane == 0) dred[wv] = dacc;
        __syncthreads();
        for (int e = tid; e < Dn; e += 256) {
            float v = sred[e] + sred[Dn + e] + sred[2 * Dn + e] + sred[3 * Dn + e];
            st_sys_f32(&sbuf[(size_t)gb * Dn + e], v);
        }
        if (tid == 0) st_sys_f32(&den[gb], dred[0] + dred[1] + dred[2] + dred[3]);
    }
    signal_ctr(ctr + CTR_TOK + (gb & 7) * 32);

    // ---------------- final GEMM + fused epilogue (blocks 0..63) ----------------
    if (gb < 64) {
        wait_tok(ctr + CTR_TOK);
        wait_ctr<8>(ctr + CTR_WOV, 64);
        wait_ctr<8>(ctr + CTR_WOZ, 8);
        int rt = gb >> 3, ct = gb & 7;
        int m0 = rt * 64, n0 = ct * 64;
        if (tid < 64) {
            float dv = ld_sys_f32(&den[m0 + tid]);
            ssv[tid] = (dv > 0.f) ? 1.f / dv : 0.f;
        }
        if (tid == 0) snv = ld_sys_i32(&nvalid[rt]);   // rows m0..m0+63 are sample rt
        __syncthreads();
        gemm_tile<true, true, true, true, false, true>(
            sbuf, m0, wov, n0, 0, 4, ssv, out, As, Bs, tid,
            snv, z, woz, bo);
    }
}

extern "C" void kernel_launch(void* const* d_in, const int* in_sizes, int n_in,
                              void* d_out, int out_size, void* d_ws, size_t ws_size,
                              hipStream_t stream) {
    const float* feats = (const float*)d_in[0];
    // d_in[1] = coords: unused by the reference
    const unsigned char* maskb = (const unsigned char*)d_in[2];
    const float* z  = (const float*)d_in[3];
    const float* Wq = (const float*)d_in[4];
    const float* Wk = (const float*)d_in[5];
    const float* Wv = (const float*)d_in[6];
    const float* Wo = (const float*)d_in[7];
    const float* bo = (const float*)d_in[8];
    float* out = (float*)d_out;

    int*   nvalid = (int*)d_ws + 16;
    int*   idx    = nvalid + 64;
    float* fbase  = (float*)(idx + Bn * Nn);
    float* qbuf   = fbase;                 // 32768 used (region 4x32768)
    float* woz    = qbuf + 4 * 32768;      // 32768 used (region 4x32768)
    float* qkp    = woz  + 4 * 32768;      // 4 x 32768 used (region 8x)
    float* wov    = qkp  + 8 * 32768;      // 262144
    float* sbuf   = wov  + 262144;         // 262144
    float* den    = sbuf + 262144;         // 1024 (padded)
    float* wp     = den  + 1024;           // counters live here
    unsigned int* ctr = (unsigned int*)wp;

    hipMemsetAsync(ctr, 0, 2048, stream);  // zero flag counters

    k_fused<<<NBLK, 256, 0, stream>>>(
        feats, maskb, z, Wq, Wk, Wv, Wo, bo, out,
        ctr, nvalid, idx, qbuf, woz, qkp, wov, sbuf, den);
}